// Round 2
// baseline (717.500 us; speedup 1.0000x reference)
//
#include <hip/hip_runtime.h>
#include <cstddef>
#include <cstdint>

// GCN 3-layer forward, MI355X. Pipeline:
//  decode edges -> deg/dinv -> CSC build (scan + fill) ->
//  agg(x,128) -> GEMM0(128x256,+b0+BN0+ReLU) -> GEMM1(256x256) ->
//  agg(256,+b1+BN1+ReLU) -> GEMM2(256x128) -> agg(128,+bl+log_softmax) -> out

#define GCN_BN_EPS 1e-5f

// ---------------------------------------------------------------- preprocess

__global__ void init_kernel(float* __restrict__ deg, int* __restrict__ cnt, int n) {
  int i = blockIdx.x * blockDim.x + threadIdx.x;
  if (i < n) { deg[i] = 1.0f; cnt[i] = 0; }  // deg starts at 1.0 (self-loop w=1)
}

// edge_index may be int32 (JAX x64 off) or int64. If int64 (little-endian) the
// odd dwords are high words == 0 since values < 50000.
__global__ void detect_kernel(const int* __restrict__ ei, int* __restrict__ flag) {
  if (blockIdx.x == 0 && threadIdx.x == 0) {
    int nz = 0;
    for (int i = 1; i < 64; i += 2) nz |= ei[i];
    *flag = (nz == 0) ? 1 : 0;  // 1 => int64 layout
  }
}

__global__ void decode_deg_kernel(const int* __restrict__ ei, const float* __restrict__ ew,
                                  const int* __restrict__ flag,
                                  int* __restrict__ row_, int* __restrict__ col_,
                                  float* __restrict__ deg, int* __restrict__ cnt, int E) {
  int e = blockIdx.x * blockDim.x + threadIdx.x;
  if (e >= E) return;
  int r, c;
  if (*flag) { r = ei[2 * e]; c = ei[2 * (E + e)]; }
  else       { r = ei[e];     c = ei[E + e]; }
  row_[e] = r; col_[e] = c;
  atomicAdd(&deg[c], ew[e]);
  atomicAdd(&cnt[c], 1);
}

__global__ void dinv_kernel(const float* __restrict__ deg, float* __restrict__ dinv, int n) {
  int i = blockIdx.x * blockDim.x + threadIdx.x;
  if (i < n) dinv[i] = rsqrtf(deg[i]);  // deg >= 1 always (self-loop)
}

// single-block hierarchical exclusive scan of cnt[0..n) -> off[0..n], cursor copy
__global__ __launch_bounds__(1024) void scan_kernel(const int* __restrict__ cnt,
                                                    int* __restrict__ off,
                                                    int* __restrict__ cursor, int n) {
  __shared__ int wsum[16];
  __shared__ int woff[16];
  __shared__ int s_carry;
  const int tid = threadIdx.x;
  const int lane = tid & 63;
  const int wv = tid >> 6;
  if (tid == 0) s_carry = 0;
  __syncthreads();
  for (int base = 0; base < n; base += 1024) {
    int i = base + tid;
    int v = (i < n) ? cnt[i] : 0;
    int x = v;
#pragma unroll
    for (int s = 1; s < 64; s <<= 1) {
      int t = __shfl_up(x, s, 64);
      if (lane >= s) x += t;
    }
    if (lane == 63) wsum[wv] = x;
    __syncthreads();
    if (wv == 0) {
      int wsv = (lane < 16) ? wsum[lane] : 0;
      int y = wsv;
#pragma unroll
      for (int s = 1; s < 16; s <<= 1) {
        int t = __shfl_up(y, s, 64);
        if (lane >= s) y += t;
      }
      if (lane < 16) woff[lane] = y - wsv;  // exclusive across waves
    }
    __syncthreads();
    int excl = x - v + woff[wv] + s_carry;
    if (i < n) { off[i] = excl; cursor[i] = excl; }
    __syncthreads();
    if (tid == 1023) s_carry += x + woff[15];  // chunk total
    __syncthreads();
  }
  if (threadIdx.x == 0) off[n] = s_carry;
}

__global__ void fill_kernel(const int* __restrict__ row_, const int* __restrict__ col_,
                            const float* __restrict__ ew, const float* __restrict__ dinv,
                            int* __restrict__ cursor,
                            int* __restrict__ csr_src, float* __restrict__ csr_val, int E) {
  int e = blockIdx.x * blockDim.x + threadIdx.x;
  if (e >= E) return;
  int r = row_[e], c = col_[e];
  int p = atomicAdd(&cursor[c], 1);
  csr_src[p] = r;
  csr_val[p] = dinv[r] * ew[e] * dinv[c];
}

// ---------------------------------------------------------------- aggregation
// out[c][f] = dinv[c]^2 * hin[c][f] + sum_{e in CSC(c)} val_e * hin[src_e][f]
// EPI: 0 plain, 1 (+bias,BN,ReLU), 2 (+bias, log_softmax; requires D==row width)
template <int D, int EPI>
__global__ __launch_bounds__(D) void agg_kernel(
    const float* __restrict__ hin, float* __restrict__ hout,
    const int* __restrict__ off, const int* __restrict__ src,
    const float* __restrict__ val, const float* __restrict__ dinv,
    const float* __restrict__ bias, const float* __restrict__ g,
    const float* __restrict__ be) {
  const int c = blockIdx.x;
  const int f = threadIdx.x;
  __shared__ int s_src[64];
  __shared__ float s_val[64];
  float di = dinv[c];
  float acc = di * di * hin[(size_t)c * D + f];
  const int e0 = off[c], e1 = off[c + 1];
  for (int base = e0; base < e1; base += 64) {
    int m = min(64, e1 - base);
    __syncthreads();
    if (f < m) { s_src[f] = src[base + f]; s_val[f] = val[base + f]; }
    __syncthreads();
    for (int i = 0; i < m; ++i)
      acc += s_val[i] * hin[(size_t)s_src[i] * D + f];
  }
  if (EPI == 0) {
    hout[(size_t)c * D + f] = acc;
  } else if (EPI == 1) {
    float s = g[f] * rsqrtf(1.0f + GCN_BN_EPS);
    float v = (acc + bias[f]) * s + be[f];
    hout[(size_t)c * D + f] = fmaxf(v, 0.0f);
  } else {
    float t = acc + bias[f];
    __shared__ float red[D];
    red[f] = t;
    __syncthreads();
#pragma unroll
    for (int s2 = D / 2; s2 > 0; s2 >>= 1) {
      if (f < s2) red[f] = fmaxf(red[f], red[f + s2]);
      __syncthreads();
    }
    float mx = red[0];
    __syncthreads();
    red[f] = expf(t - mx);
    __syncthreads();
#pragma unroll
    for (int s2 = D / 2; s2 > 0; s2 >>= 1) {
      if (f < s2) red[f] += red[f + s2];
      __syncthreads();
    }
    float lse = logf(red[0]) + mx;
    hout[(size_t)c * D + f] = t - lse;
  }
}

// ---------------------------------------------------------------- fp32 GEMM
// C[M,Nc] = A[M,K] @ W[K,Nc]; tile 128x128, BK=32, 256 thr, 8x8/thread.
// epi 0: plain store; epi 1: relu((acc+bias)*g*rsqrt(1+eps)+be)
#define GB_M 128
#define GB_N 128
#define GB_K 32

__global__ __launch_bounds__(256, 2) void gemm_kernel(
    const float* __restrict__ A, const float* __restrict__ W,
    float* __restrict__ C, int M, int K, int Nc, int epi,
    const float* __restrict__ bias, const float* __restrict__ g,
    const float* __restrict__ be) {
  __shared__ float As[GB_K][132];   // transposed A tile, pad 128->132 (16B-aligned rows)
  __shared__ float Ws[GB_K][GB_N];
  const int tid = threadIdx.x;
  const int tx = tid & 15;   // col group
  const int ty = tid >> 4;   // row group
  const int row0 = blockIdx.y * GB_M;
  const int col0 = blockIdx.x * GB_N;

  float acc[2][4][2][4];  // [i4][i][j4][j]
#pragma unroll
  for (int a = 0; a < 2; ++a)
#pragma unroll
    for (int b = 0; b < 4; ++b)
#pragma unroll
      for (int cc = 0; cc < 2; ++cc)
#pragma unroll
        for (int d = 0; d < 4; ++d) acc[a][b][cc][d] = 0.0f;

  const int kq = tid & 7;         // A-stage k quad
  const int rl = tid >> 3;        // A-stage row 0..31
  const int wc4 = (tid & 31) * 4; // W-stage col
  const int wkr = tid >> 5;       // W-stage k row 0..7

  for (int k0 = 0; k0 < K; k0 += GB_K) {
#pragma unroll
    for (int p = 0; p < 4; ++p) {
      int r = rl + 32 * p;
      int grow = row0 + r;
      float4 v = make_float4(0.f, 0.f, 0.f, 0.f);
      if (grow < M) v = *(const float4*)&A[(size_t)grow * K + k0 + kq * 4];
      As[kq * 4 + 0][r] = v.x;
      As[kq * 4 + 1][r] = v.y;
      As[kq * 4 + 2][r] = v.z;
      As[kq * 4 + 3][r] = v.w;
    }
#pragma unroll
    for (int p = 0; p < 4; ++p) {
      int kk = wkr + 8 * p;
      *(float4*)&Ws[kk][wc4] = *(const float4*)&W[(size_t)(k0 + kk) * Nc + col0 + wc4];
    }
    __syncthreads();
#pragma unroll
    for (int kk = 0; kk < GB_K; ++kk) {
      float4 a0 = *(const float4*)&As[kk][ty * 4];
      float4 a1 = *(const float4*)&As[kk][ty * 4 + 64];
      float4 w0 = *(const float4*)&Ws[kk][tx * 4];
      float4 w1 = *(const float4*)&Ws[kk][tx * 4 + 64];
      float av[2][4] = {{a0.x, a0.y, a0.z, a0.w}, {a1.x, a1.y, a1.z, a1.w}};
      float wv[2][4] = {{w0.x, w0.y, w0.z, w0.w}, {w1.x, w1.y, w1.z, w1.w}};
#pragma unroll
      for (int i4 = 0; i4 < 2; ++i4)
#pragma unroll
        for (int i = 0; i < 4; ++i) {
          float a = av[i4][i];
#pragma unroll
          for (int j4 = 0; j4 < 2; ++j4)
#pragma unroll
            for (int j = 0; j < 4; ++j) acc[i4][i][j4][j] += a * wv[j4][j];
        }
    }
    __syncthreads();
  }

  const float bnscale = rsqrtf(1.0f + GCN_BN_EPS);
  float4 bi[2], gi[2], bei[2];
  if (epi == 1) {
#pragma unroll
    for (int j4 = 0; j4 < 2; ++j4) {
      int c = col0 + j4 * 64 + tx * 4;
      bi[j4] = *(const float4*)&bias[c];
      gi[j4] = *(const float4*)&g[c];
      bei[j4] = *(const float4*)&be[c];
    }
  }
#pragma unroll
  for (int i4 = 0; i4 < 2; ++i4)
#pragma unroll
    for (int i = 0; i < 4; ++i) {
      int r = row0 + i4 * 64 + ty * 4 + i;
      if (r >= M) continue;
#pragma unroll
      for (int j4 = 0; j4 < 2; ++j4) {
        int c = col0 + j4 * 64 + tx * 4;
        float4 res = make_float4(acc[i4][i][j4][0], acc[i4][i][j4][1],
                                 acc[i4][i][j4][2], acc[i4][i][j4][3]);
        if (epi == 1) {
          res.x = fmaxf((res.x + bi[j4].x) * gi[j4].x * bnscale + bei[j4].x, 0.f);
          res.y = fmaxf((res.y + bi[j4].y) * gi[j4].y * bnscale + bei[j4].y, 0.f);
          res.z = fmaxf((res.z + bi[j4].z) * gi[j4].z * bnscale + bei[j4].z, 0.f);
          res.w = fmaxf((res.w + bi[j4].w) * gi[j4].w * bnscale + bei[j4].w, 0.f);
        }
        *(float4*)&C[(size_t)r * Nc + c] = res;
      }
    }
}

// ---------------------------------------------------------------- launch

static inline char* carve(char*& p, size_t bytes) {
  char* r = p;
  p += (bytes + 255) & ~(size_t)255;
  return r;
}

extern "C" void kernel_launch(void* const* d_in, const int* in_sizes, int n_in,
                              void* d_out, int out_size, void* d_ws, size_t ws_size,
                              hipStream_t stream) {
  const int N = in_sizes[0] / 128;
  const int E = in_sizes[2];

  const float* x  = (const float*)d_in[0];
  const int*   ei = (const int*)d_in[1];
  const float* ew = (const float*)d_in[2];
  const float* W0 = (const float*)d_in[3];
  const float* b0 = (const float*)d_in[4];
  const float* W1 = (const float*)d_in[5];
  const float* b1 = (const float*)d_in[6];
  const float* Wl = (const float*)d_in[7];
  const float* bl = (const float*)d_in[8];
  const float* g0 = (const float*)d_in[9];
  const float* be0 = (const float*)d_in[10];
  const float* g1 = (const float*)d_in[11];
  const float* be1 = (const float*)d_in[12];
  float* out = (float*)d_out;

  char* p = (char*)d_ws;
  float* deg     = (float*)carve(p, (size_t)N * 4);
  float* dinv    = (float*)carve(p, (size_t)N * 4);
  int*   cnt     = (int*)carve(p, (size_t)N * 4);
  int*   cursor  = (int*)carve(p, (size_t)N * 4);
  int*   off     = (int*)carve(p, (size_t)(N + 1) * 4);
  int*   flag    = (int*)carve(p, 256);
  int*   row_    = (int*)carve(p, (size_t)E * 4);
  int*   col_    = (int*)carve(p, (size_t)E * 4);
  int*   csr_src = (int*)carve(p, (size_t)E * 4);
  float* csr_val = (float*)carve(p, (size_t)E * 4);
  float* bufA    = (float*)carve(p, (size_t)N * 256 * 4);
  float* bufB    = (float*)carve(p, (size_t)N * 256 * 4);

  const int TB = 256;
  const int gN = (N + TB - 1) / TB;
  const int gE = (E + TB - 1) / TB;

  init_kernel<<<gN, TB, 0, stream>>>(deg, cnt, N);
  detect_kernel<<<1, 64, 0, stream>>>(ei, flag);
  decode_deg_kernel<<<gE, TB, 0, stream>>>(ei, ew, flag, row_, col_, deg, cnt, E);
  dinv_kernel<<<gN, TB, 0, stream>>>(deg, dinv, N);
  scan_kernel<<<1, 1024, 0, stream>>>(cnt, off, cursor, N);
  fill_kernel<<<gE, TB, 0, stream>>>(row_, col_, ew, dinv, cursor, csr_src, csr_val, E);

  // layer 0: agg(x) -> bufA[N,128]; GEMM0 + b0 + BN0 + ReLU -> bufB[N,256]
  agg_kernel<128, 0><<<N, 128, 0, stream>>>(x, bufA, off, csr_src, csr_val, dinv,
                                            nullptr, nullptr, nullptr);
  {
    dim3 grid(256 / GB_N, (N + GB_M - 1) / GB_M);
    gemm_kernel<<<grid, 256, 0, stream>>>(bufA, W0, bufB, N, 128, 256, 1, b0, g0, be0);
  }
  // layer 1: GEMM1 -> bufA[N,256]; agg + b1 + BN1 + ReLU -> bufB[N,256]
  {
    dim3 grid(256 / GB_N, (N + GB_M - 1) / GB_M);
    gemm_kernel<<<grid, 256, 0, stream>>>(bufB, W1, bufA, N, 256, 256, 0,
                                          nullptr, nullptr, nullptr);
  }
  agg_kernel<256, 1><<<N, 256, 0, stream>>>(bufA, bufB, off, csr_src, csr_val, dinv,
                                            b1, g1, be1);
  // layer 2: GEMM2 -> bufA[N,128]; agg + bl + log_softmax -> out
  {
    dim3 grid(128 / GB_N, (N + GB_M - 1) / GB_M);
    gemm_kernel<<<grid, 256, 0, stream>>>(bufB, Wl, bufA, N, 256, 128, 0,
                                          nullptr, nullptr, nullptr);
  }
  agg_kernel<128, 2><<<N, 128, 0, stream>>>(bufA, out, off, csr_src, csr_val, dinv,
                                            bl, nullptr, nullptr);
}

// Round 3
// 673.705 us; speedup vs baseline: 1.0650x; 1.0650x over previous
//
#include <hip/hip_runtime.h>
#include <cstddef>
#include <cstdint>

// GCN 3-layer forward, MI355X.
//  decode edges -> deg/dinv -> CSC build (3-phase parallel scan + fill) ->
//  agg(x,128) -> GEMM0(128x256,+b0+BN0+ReLU) -> GEMM1(256x256) ->
//  agg(256,+b1+BN1+ReLU) -> GEMM2(256x128) -> agg(128,+bl+log_softmax) -> out
// Aggregation: one wave per destination node, edge meta broadcast via shfl,
// float4/float2 gathers, no barriers (R2: was LDS-staged + 2 barriers/chunk,
// latency-bound at 48% HBM BW / 28% VALU).

#define GCN_BN_EPS 1e-5f

// ---------------------------------------------------------------- preprocess

__global__ void init_detect_kernel(float* __restrict__ deg, int* __restrict__ cnt,
                                   const int* __restrict__ ei, int* __restrict__ flag,
                                   int n) {
  int i = blockIdx.x * blockDim.x + threadIdx.x;
  if (i < n) { deg[i] = 1.0f; cnt[i] = 0; }  // deg starts at 1.0 (self-loop w=1)
  if (blockIdx.x == 0 && threadIdx.x == 0) {
    // edge_index may be int32 or int64; if int64, high dwords are 0 (vals<50k)
    int nz = 0;
    for (int k = 1; k < 64; k += 2) nz |= ei[k];
    *flag = (nz == 0) ? 1 : 0;  // 1 => int64 layout
  }
}

__global__ void decode_deg_kernel(const int* __restrict__ ei, const float* __restrict__ ew,
                                  const int* __restrict__ flag,
                                  int* __restrict__ row_, int* __restrict__ col_,
                                  float* __restrict__ deg, int* __restrict__ cnt, int E) {
  int e = blockIdx.x * blockDim.x + threadIdx.x;
  if (e >= E) return;
  int r, c;
  if (*flag) { r = ei[2 * e]; c = ei[2 * (E + e)]; }
  else       { r = ei[e];     c = ei[E + e]; }
  row_[e] = r; col_[e] = c;
  atomicAdd(&deg[c], ew[e]);
  atomicAdd(&cnt[c], 1);
}

// phase 1: per-256-block sums of cnt; also dinv = rsqrt(deg)
__global__ __launch_bounds__(256) void scan1_kernel(const int* __restrict__ cnt,
                                                    const float* __restrict__ deg,
                                                    float* __restrict__ dinv,
                                                    int* __restrict__ bsum, int n) {
  __shared__ int ws[4];
  int i = blockIdx.x * 256 + threadIdx.x;
  int v = (i < n) ? cnt[i] : 0;
  if (i < n) dinv[i] = rsqrtf(deg[i]);  // deg >= 1 always
  int x = v;
#pragma unroll
  for (int s = 1; s < 64; s <<= 1) x += __shfl_xor(x, s, 64);
  if ((threadIdx.x & 63) == 0) ws[threadIdx.x >> 6] = x;
  __syncthreads();
  if (threadIdx.x == 0) bsum[blockIdx.x] = ws[0] + ws[1] + ws[2] + ws[3];
}

// phase 2: exclusive scan of bsum[G] in place (G <= 1024); off[n] = E
__global__ __launch_bounds__(1024) void scan2_kernel(int* __restrict__ bsum, int G,
                                                     int* __restrict__ off, int n, int E) {
  __shared__ int wsum[16], woff[16];
  int tid = threadIdx.x, lane = tid & 63, wv = tid >> 6;
  int v = (tid < G) ? bsum[tid] : 0;
  int x = v;
#pragma unroll
  for (int s = 1; s < 64; s <<= 1) { int t = __shfl_up(x, s, 64); if (lane >= s) x += t; }
  if (lane == 63) wsum[wv] = x;
  __syncthreads();
  if (wv == 0) {
    int wsv = (lane < 16) ? wsum[lane] : 0;
    int y = wsv;
#pragma unroll
    for (int s = 1; s < 16; s <<= 1) { int t = __shfl_up(y, s, 64); if (lane >= s) y += t; }
    if (lane < 16) woff[lane] = y - wsv;
  }
  __syncthreads();
  if (tid < G) bsum[tid] = x - v + woff[wv];  // exclusive base per block
  if (tid == 0) off[n] = E;                   // total in-edges == E analytically
}

// phase 3: off[i] = bsum[blk] + exclusive-within-block; cursor copy
__global__ __launch_bounds__(256) void scan3_kernel(const int* __restrict__ cnt,
                                                    const int* __restrict__ bsum,
                                                    int* __restrict__ off,
                                                    int* __restrict__ cursor, int n) {
  __shared__ int wsum[4], woff[4];
  int tid = threadIdx.x, lane = tid & 63, wv = tid >> 6;
  int i = blockIdx.x * 256 + tid;
  int v = (i < n) ? cnt[i] : 0;
  int x = v;
#pragma unroll
  for (int s = 1; s < 64; s <<= 1) { int t = __shfl_up(x, s, 64); if (lane >= s) x += t; }
  if (lane == 63) wsum[wv] = x;
  __syncthreads();
  if (tid == 0) { int r = 0; for (int k = 0; k < 4; ++k) { woff[k] = r; r += wsum[k]; } }
  __syncthreads();
  if (i < n) {
    int excl = x - v + woff[wv] + bsum[blockIdx.x];
    off[i] = excl;
    cursor[i] = excl;
  }
}

__global__ void fill_kernel(const int* __restrict__ row_, const int* __restrict__ col_,
                            const float* __restrict__ ew, const float* __restrict__ dinv,
                            int* __restrict__ cursor,
                            int* __restrict__ csr_src, float* __restrict__ csr_val, int E) {
  int e = blockIdx.x * blockDim.x + threadIdx.x;
  if (e >= E) return;
  int r = row_[e], c = col_[e];
  int p = atomicAdd(&cursor[c], 1);
  csr_src[p] = r;
  csr_val[p] = dinv[r] * ew[e] * dinv[c];
}

// ---------------------------------------------------------------- aggregation
// out[c][f] = dinv[c]^2 * hin[c][f] + sum_{e in CSC(c)} val_e * hin[src_e][f]
// One wave per node; edge (src,val) in registers, broadcast via shfl; no LDS.

// D=256: lane holds 4 feats (float4). EPI 0 plain, 1 (+bias,BN,ReLU)
template <int EPI>
__global__ __launch_bounds__(256) void agg256_kernel(
    const float* __restrict__ hin, float* __restrict__ hout,
    const int* __restrict__ off, const int* __restrict__ src,
    const float* __restrict__ val, const float* __restrict__ dinv,
    const float* __restrict__ bias, const float* __restrict__ g,
    const float* __restrict__ be, int n) {
  const int lane = threadIdx.x & 63;
  const int c = blockIdx.x * 4 + (threadIdx.x >> 6);
  if (c >= n) return;
  const int f4 = lane * 4;
  const float di = dinv[c];
  const float s2 = di * di;
  float4 self = *(const float4*)&hin[(size_t)c * 256 + f4];
  float4 acc = make_float4(self.x * s2, self.y * s2, self.z * s2, self.w * s2);
  const int e0 = off[c], e1 = off[c + 1];
  for (int base = e0; base < e1; base += 64) {
    int idx = base + lane;
    int rs = 0; float rv = 0.0f;
    if (idx < e1) { rs = src[idx]; rv = val[idx]; }
    const int m = min(64, e1 - base);
    int i = 0;
    for (; i + 4 <= m; i += 4) {
      int s0 = __shfl(rs, i);     float v0 = __shfl(rv, i);
      int s1 = __shfl(rs, i + 1); float v1 = __shfl(rv, i + 1);
      int sB = __shfl(rs, i + 2); float v2 = __shfl(rv, i + 2);
      int s3 = __shfl(rs, i + 3); float v3 = __shfl(rv, i + 3);
      float4 h0 = *(const float4*)&hin[(size_t)s0 * 256 + f4];
      float4 h1 = *(const float4*)&hin[(size_t)s1 * 256 + f4];
      float4 h2 = *(const float4*)&hin[(size_t)sB * 256 + f4];
      float4 h3 = *(const float4*)&hin[(size_t)s3 * 256 + f4];
      acc.x += v0 * h0.x + v1 * h1.x + v2 * h2.x + v3 * h3.x;
      acc.y += v0 * h0.y + v1 * h1.y + v2 * h2.y + v3 * h3.y;
      acc.z += v0 * h0.z + v1 * h1.z + v2 * h2.z + v3 * h3.z;
      acc.w += v0 * h0.w + v1 * h1.w + v2 * h2.w + v3 * h3.w;
    }
    for (; i < m; ++i) {
      int s = __shfl(rs, i); float v = __shfl(rv, i);
      float4 hv = *(const float4*)&hin[(size_t)s * 256 + f4];
      acc.x += v * hv.x; acc.y += v * hv.y; acc.z += v * hv.z; acc.w += v * hv.w;
    }
  }
  if (EPI == 1) {
    const float bns = rsqrtf(1.0f + GCN_BN_EPS);
    float4 bi = *(const float4*)&bias[f4];
    float4 gi = *(const float4*)&g[f4];
    float4 bei = *(const float4*)&be[f4];
    acc.x = fmaxf((acc.x + bi.x) * gi.x * bns + bei.x, 0.0f);
    acc.y = fmaxf((acc.y + bi.y) * gi.y * bns + bei.y, 0.0f);
    acc.z = fmaxf((acc.z + bi.z) * gi.z * bns + bei.z, 0.0f);
    acc.w = fmaxf((acc.w + bi.w) * gi.w * bns + bei.w, 0.0f);
  }
  *(float4*)&hout[(size_t)c * 256 + f4] = acc;
}

// D=128: lane holds 2 feats (float2). EPI 0 plain, 2 (+bias, log_softmax)
template <int EPI>
__global__ __launch_bounds__(256) void agg128_kernel(
    const float* __restrict__ hin, float* __restrict__ hout,
    const int* __restrict__ off, const int* __restrict__ src,
    const float* __restrict__ val, const float* __restrict__ dinv,
    const float* __restrict__ bias, int n) {
  const int lane = threadIdx.x & 63;
  const int c = blockIdx.x * 4 + (threadIdx.x >> 6);
  if (c >= n) return;
  const int f2 = lane * 2;
  const float di = dinv[c];
  const float s2 = di * di;
  float2 self = *(const float2*)&hin[(size_t)c * 128 + f2];
  float2 acc = make_float2(self.x * s2, self.y * s2);
  const int e0 = off[c], e1 = off[c + 1];
  for (int base = e0; base < e1; base += 64) {
    int idx = base + lane;
    int rs = 0; float rv = 0.0f;
    if (idx < e1) { rs = src[idx]; rv = val[idx]; }
    const int m = min(64, e1 - base);
    int i = 0;
    for (; i + 4 <= m; i += 4) {
      int s0 = __shfl(rs, i);     float v0 = __shfl(rv, i);
      int s1 = __shfl(rs, i + 1); float v1 = __shfl(rv, i + 1);
      int sB = __shfl(rs, i + 2); float v2 = __shfl(rv, i + 2);
      int s3 = __shfl(rs, i + 3); float v3 = __shfl(rv, i + 3);
      float2 h0 = *(const float2*)&hin[(size_t)s0 * 128 + f2];
      float2 h1 = *(const float2*)&hin[(size_t)s1 * 128 + f2];
      float2 h2 = *(const float2*)&hin[(size_t)sB * 128 + f2];
      float2 h3 = *(const float2*)&hin[(size_t)s3 * 128 + f2];
      acc.x += v0 * h0.x + v1 * h1.x + v2 * h2.x + v3 * h3.x;
      acc.y += v0 * h0.y + v1 * h1.y + v2 * h2.y + v3 * h3.y;
    }
    for (; i < m; ++i) {
      int s = __shfl(rs, i); float v = __shfl(rv, i);
      float2 hv = *(const float2*)&hin[(size_t)s * 128 + f2];
      acc.x += v * hv.x; acc.y += v * hv.y;
    }
  }
  if (EPI == 0) {
    *(float2*)&hout[(size_t)c * 128 + f2] = acc;
  } else {
    float2 bi = *(const float2*)&bias[f2];
    float tx = acc.x + bi.x, ty = acc.y + bi.y;
    float mx = fmaxf(tx, ty);
#pragma unroll
    for (int s = 1; s < 64; s <<= 1) mx = fmaxf(mx, __shfl_xor(mx, s, 64));
    float ex = expf(tx - mx) + expf(ty - mx);
#pragma unroll
    for (int s = 1; s < 64; s <<= 1) ex += __shfl_xor(ex, s, 64);
    float lse = logf(ex) + mx;
    float2 res = make_float2(tx - lse, ty - lse);
    *(float2*)&hout[(size_t)c * 128 + f2] = res;
  }
}

// ---------------------------------------------------------------- fp32 GEMM
// C[M,Nc] = A[M,K] @ W[K,Nc]; tile 128x128, BK=32, 256 thr, 8x8/thread.
// epi 0: plain store; epi 1: relu((acc+bias)*g*rsqrt(1+eps)+be)
#define GB_M 128
#define GB_N 128
#define GB_K 32

__global__ __launch_bounds__(256, 2) void gemm_kernel(
    const float* __restrict__ A, const float* __restrict__ W,
    float* __restrict__ C, int M, int K, int Nc, int epi,
    const float* __restrict__ bias, const float* __restrict__ g,
    const float* __restrict__ be) {
  __shared__ float As[GB_K][132];   // transposed A tile, pad 128->132 (16B-aligned rows)
  __shared__ float Ws[GB_K][GB_N];
  const int tid = threadIdx.x;
  const int tx = tid & 15;   // col group
  const int ty = tid >> 4;   // row group
  const int row0 = blockIdx.y * GB_M;
  const int col0 = blockIdx.x * GB_N;

  float acc[2][4][2][4];  // [i4][i][j4][j]
#pragma unroll
  for (int a = 0; a < 2; ++a)
#pragma unroll
    for (int b = 0; b < 4; ++b)
#pragma unroll
      for (int cc = 0; cc < 2; ++cc)
#pragma unroll
        for (int d = 0; d < 4; ++d) acc[a][b][cc][d] = 0.0f;

  const int kq = tid & 7;         // A-stage k quad
  const int rl = tid >> 3;        // A-stage row 0..31
  const int wc4 = (tid & 31) * 4; // W-stage col
  const int wkr = tid >> 5;       // W-stage k row 0..7

  for (int k0 = 0; k0 < K; k0 += GB_K) {
#pragma unroll
    for (int p = 0; p < 4; ++p) {
      int r = rl + 32 * p;
      int grow = row0 + r;
      float4 v = make_float4(0.f, 0.f, 0.f, 0.f);
      if (grow < M) v = *(const float4*)&A[(size_t)grow * K + k0 + kq * 4];
      As[kq * 4 + 0][r] = v.x;
      As[kq * 4 + 1][r] = v.y;
      As[kq * 4 + 2][r] = v.z;
      As[kq * 4 + 3][r] = v.w;
    }
#pragma unroll
    for (int p = 0; p < 4; ++p) {
      int kk = wkr + 8 * p;
      *(float4*)&Ws[kk][wc4] = *(const float4*)&W[(size_t)(k0 + kk) * Nc + col0 + wc4];
    }
    __syncthreads();
#pragma unroll
    for (int kk = 0; kk < GB_K; ++kk) {
      float4 a0 = *(const float4*)&As[kk][ty * 4];
      float4 a1 = *(const float4*)&As[kk][ty * 4 + 64];
      float4 w0 = *(const float4*)&Ws[kk][tx * 4];
      float4 w1 = *(const float4*)&Ws[kk][tx * 4 + 64];
      float av[2][4] = {{a0.x, a0.y, a0.z, a0.w}, {a1.x, a1.y, a1.z, a1.w}};
      float wv[2][4] = {{w0.x, w0.y, w0.z, w0.w}, {w1.x, w1.y, w1.z, w1.w}};
#pragma unroll
      for (int i4 = 0; i4 < 2; ++i4)
#pragma unroll
        for (int i = 0; i < 4; ++i) {
          float a = av[i4][i];
#pragma unroll
          for (int j4 = 0; j4 < 2; ++j4)
#pragma unroll
            for (int j = 0; j < 4; ++j) acc[i4][i][j4][j] += a * wv[j4][j];
        }
    }
    __syncthreads();
  }

  const float bnscale = rsqrtf(1.0f + GCN_BN_EPS);
  float4 bi[2], gi[2], bei[2];
  if (epi == 1) {
#pragma unroll
    for (int j4 = 0; j4 < 2; ++j4) {
      int c = col0 + j4 * 64 + tx * 4;
      bi[j4] = *(const float4*)&bias[c];
      gi[j4] = *(const float4*)&g[c];
      bei[j4] = *(const float4*)&be[c];
    }
  }
#pragma unroll
  for (int i4 = 0; i4 < 2; ++i4)
#pragma unroll
    for (int i = 0; i < 4; ++i) {
      int r = row0 + i4 * 64 + ty * 4 + i;
      if (r >= M) continue;
#pragma unroll
      for (int j4 = 0; j4 < 2; ++j4) {
        int c = col0 + j4 * 64 + tx * 4;
        float4 res = make_float4(acc[i4][i][j4][0], acc[i4][i][j4][1],
                                 acc[i4][i][j4][2], acc[i4][i][j4][3]);
        if (epi == 1) {
          res.x = fmaxf((res.x + bi[j4].x) * gi[j4].x * bnscale + bei[j4].x, 0.f);
          res.y = fmaxf((res.y + bi[j4].y) * gi[j4].y * bnscale + bei[j4].y, 0.f);
          res.z = fmaxf((res.z + bi[j4].z) * gi[j4].z * bnscale + bei[j4].z, 0.f);
          res.w = fmaxf((res.w + bi[j4].w) * gi[j4].w * bnscale + bei[j4].w, 0.f);
        }
        *(float4*)&C[(size_t)r * Nc + c] = res;
      }
    }
}

// ---------------------------------------------------------------- launch

static inline char* carve(char*& p, size_t bytes) {
  char* r = p;
  p += (bytes + 255) & ~(size_t)255;
  return r;
}

extern "C" void kernel_launch(void* const* d_in, const int* in_sizes, int n_in,
                              void* d_out, int out_size, void* d_ws, size_t ws_size,
                              hipStream_t stream) {
  const int N = in_sizes[0] / 128;
  const int E = in_sizes[2];

  const float* x  = (const float*)d_in[0];
  const int*   ei = (const int*)d_in[1];
  const float* ew = (const float*)d_in[2];
  const float* W0 = (const float*)d_in[3];
  const float* b0 = (const float*)d_in[4];
  const float* W1 = (const float*)d_in[5];
  const float* b1 = (const float*)d_in[6];
  const float* Wl = (const float*)d_in[7];
  const float* bl = (const float*)d_in[8];
  const float* g0 = (const float*)d_in[9];
  const float* be0 = (const float*)d_in[10];
  const float* g1 = (const float*)d_in[11];
  const float* be1 = (const float*)d_in[12];
  float* out = (float*)d_out;

  char* p = (char*)d_ws;
  float* deg     = (float*)carve(p, (size_t)N * 4);
  float* dinv    = (float*)carve(p, (size_t)N * 4);
  int*   cnt     = (int*)carve(p, (size_t)N * 4);
  int*   cursor  = (int*)carve(p, (size_t)N * 4);
  int*   off     = (int*)carve(p, (size_t)(N + 1) * 4);
  int*   flag    = (int*)carve(p, 256);
  int*   bsum    = (int*)carve(p, 1024 * 4);
  int*   row_    = (int*)carve(p, (size_t)E * 4);
  int*   col_    = (int*)carve(p, (size_t)E * 4);
  int*   csr_src = (int*)carve(p, (size_t)E * 4);
  float* csr_val = (float*)carve(p, (size_t)E * 4);
  float* bufA    = (float*)carve(p, (size_t)N * 256 * 4);
  float* bufB    = (float*)carve(p, (size_t)N * 256 * 4);

  const int TB = 256;
  const int gN = (N + TB - 1) / TB;   // 196
  const int gE = (E + TB - 1) / TB;
  const int gW = (N + 3) / 4;         // 4 nodes (waves) per block

  init_detect_kernel<<<gN, TB, 0, stream>>>(deg, cnt, ei, flag, N);
  decode_deg_kernel<<<gE, TB, 0, stream>>>(ei, ew, flag, row_, col_, deg, cnt, E);
  scan1_kernel<<<gN, TB, 0, stream>>>(cnt, deg, dinv, bsum, N);
  scan2_kernel<<<1, 1024, 0, stream>>>(bsum, gN, off, N, E);
  scan3_kernel<<<gN, TB, 0, stream>>>(cnt, bsum, off, cursor, N);
  fill_kernel<<<gE, TB, 0, stream>>>(row_, col_, ew, dinv, cursor, csr_src, csr_val, E);

  // layer 0: agg(x,128) -> bufA; GEMM0 + b0 + BN0 + ReLU -> bufB[N,256]
  agg128_kernel<0><<<gW, 256, 0, stream>>>(x, bufA, off, csr_src, csr_val, dinv,
                                           nullptr, N);
  {
    dim3 grid(256 / GB_N, (N + GB_M - 1) / GB_M);
    gemm_kernel<<<grid, 256, 0, stream>>>(bufA, W0, bufB, N, 128, 256, 1, b0, g0, be0);
  }
  // layer 1: GEMM1 -> bufA[N,256]; agg + b1 + BN1 + ReLU -> bufB[N,256]
  {
    dim3 grid(256 / GB_N, (N + GB_M - 1) / GB_M);
    gemm_kernel<<<grid, 256, 0, stream>>>(bufB, W1, bufA, N, 256, 256, 0,
                                          nullptr, nullptr, nullptr);
  }
  agg256_kernel<1><<<gW, 256, 0, stream>>>(bufA, bufB, off, csr_src, csr_val, dinv,
                                           b1, g1, be1, N);
  // layer 2: GEMM2 -> bufA[N,128]; agg + bl + log_softmax -> out
  {
    dim3 grid(128 / GB_N, (N + GB_M - 1) / GB_M);
    gemm_kernel<<<grid, 256, 0, stream>>>(bufB, Wl, bufA, N, 256, 128, 0,
                                          nullptr, nullptr, nullptr);
  }
  agg128_kernel<2><<<gW, 256, 0, stream>>>(bufA, out, off, csr_src, csr_val, dinv,
                                           bl, N);
}

// Round 4
// 663.424 us; speedup vs baseline: 1.0815x; 1.0155x over previous
//
#include <hip/hip_runtime.h>
#include <cstddef>
#include <cstdint>

// GCN 3-layer forward, MI355X.
//  decode edges -> deg/dinv -> CSC build (3-phase parallel scan + fill) ->
//  agg(x,128) -> GEMM0(128x256,+b0+BN0+ReLU) -> GEMM1(256x256) ->
//  agg(256,+b1+BN1+ReLU) -> GEMM2(256x128) -> agg(128,+bl+log_softmax) -> out
// R4: agg kernels get depth-2 software-pipelined gathers (ping-pong register
// buffers, zero-padded uniform 4-edge groups); agg128 packs 2 nodes/wave
// (half-wave float4). Tests the latency-bound hypothesis (R3: 3.6 TB/s,
// VALU 10%, nothing saturated).

#define GCN_BN_EPS 1e-5f

// ---------------------------------------------------------------- preprocess

__global__ void init_detect_kernel(float* __restrict__ deg, int* __restrict__ cnt,
                                   const int* __restrict__ ei, int* __restrict__ flag,
                                   int n) {
  int i = blockIdx.x * blockDim.x + threadIdx.x;
  if (i < n) { deg[i] = 1.0f; cnt[i] = 0; }  // deg starts at 1.0 (self-loop w=1)
  if (blockIdx.x == 0 && threadIdx.x == 0) {
    // edge_index may be int32 or int64; if int64, high dwords are 0 (vals<50k)
    int nz = 0;
    for (int k = 1; k < 64; k += 2) nz |= ei[k];
    *flag = (nz == 0) ? 1 : 0;  // 1 => int64 layout
  }
}

__global__ void decode_deg_kernel(const int* __restrict__ ei, const float* __restrict__ ew,
                                  const int* __restrict__ flag,
                                  int* __restrict__ row_, int* __restrict__ col_,
                                  float* __restrict__ deg, int* __restrict__ cnt, int E) {
  int e = blockIdx.x * blockDim.x + threadIdx.x;
  if (e >= E) return;
  int r, c;
  if (*flag) { r = ei[2 * e]; c = ei[2 * (E + e)]; }
  else       { r = ei[e];     c = ei[E + e]; }
  row_[e] = r; col_[e] = c;
  atomicAdd(&deg[c], ew[e]);
  atomicAdd(&cnt[c], 1);
}

// phase 1: per-256-block sums of cnt; also dinv = rsqrt(deg)
__global__ __launch_bounds__(256) void scan1_kernel(const int* __restrict__ cnt,
                                                    const float* __restrict__ deg,
                                                    float* __restrict__ dinv,
                                                    int* __restrict__ bsum, int n) {
  __shared__ int ws[4];
  int i = blockIdx.x * 256 + threadIdx.x;
  int v = (i < n) ? cnt[i] : 0;
  if (i < n) dinv[i] = rsqrtf(deg[i]);  // deg >= 1 always
  int x = v;
#pragma unroll
  for (int s = 1; s < 64; s <<= 1) x += __shfl_xor(x, s, 64);
  if ((threadIdx.x & 63) == 0) ws[threadIdx.x >> 6] = x;
  __syncthreads();
  if (threadIdx.x == 0) bsum[blockIdx.x] = ws[0] + ws[1] + ws[2] + ws[3];
}

// phase 2: exclusive scan of bsum[G] in place (G <= 1024); off[n] = E
__global__ __launch_bounds__(1024) void scan2_kernel(int* __restrict__ bsum, int G,
                                                     int* __restrict__ off, int n, int E) {
  __shared__ int wsum[16], woff[16];
  int tid = threadIdx.x, lane = tid & 63, wv = tid >> 6;
  int v = (tid < G) ? bsum[tid] : 0;
  int x = v;
#pragma unroll
  for (int s = 1; s < 64; s <<= 1) { int t = __shfl_up(x, s, 64); if (lane >= s) x += t; }
  if (lane == 63) wsum[wv] = x;
  __syncthreads();
  if (wv == 0) {
    int wsv = (lane < 16) ? wsum[lane] : 0;
    int y = wsv;
#pragma unroll
    for (int s = 1; s < 16; s <<= 1) { int t = __shfl_up(y, s, 64); if (lane >= s) y += t; }
    if (lane < 16) woff[lane] = y - wsv;
  }
  __syncthreads();
  if (tid < G) bsum[tid] = x - v + woff[wv];  // exclusive base per block
  if (tid == 0) off[n] = E;                   // total in-edges == E analytically
}

// phase 3: off[i] = bsum[blk] + exclusive-within-block; cursor copy
__global__ __launch_bounds__(256) void scan3_kernel(const int* __restrict__ cnt,
                                                    const int* __restrict__ bsum,
                                                    int* __restrict__ off,
                                                    int* __restrict__ cursor, int n) {
  __shared__ int wsum[4], woff[4];
  int tid = threadIdx.x, lane = tid & 63, wv = tid >> 6;
  int i = blockIdx.x * 256 + tid;
  int v = (i < n) ? cnt[i] : 0;
  int x = v;
#pragma unroll
  for (int s = 1; s < 64; s <<= 1) { int t = __shfl_up(x, s, 64); if (lane >= s) x += t; }
  if (lane == 63) wsum[wv] = x;
  __syncthreads();
  if (tid == 0) { int r = 0; for (int k = 0; k < 4; ++k) { woff[k] = r; r += wsum[k]; } }
  __syncthreads();
  if (i < n) {
    int excl = x - v + woff[wv] + bsum[blockIdx.x];
    off[i] = excl;
    cursor[i] = excl;
  }
}

__global__ void fill_kernel(const int* __restrict__ row_, const int* __restrict__ col_,
                            const float* __restrict__ ew, const float* __restrict__ dinv,
                            int* __restrict__ cursor,
                            int* __restrict__ csr_src, float* __restrict__ csr_val, int E) {
  int e = blockIdx.x * blockDim.x + threadIdx.x;
  if (e >= E) return;
  int r = row_[e], c = col_[e];
  int p = atomicAdd(&cursor[c], 1);
  csr_src[p] = r;
  csr_val[p] = dinv[r] * ew[e] * dinv[c];
}

// ---------------------------------------------------------------- aggregation
// out[c][f] = dinv[c]^2 * hin[c][f] + sum_{e in CSC(c)} val_e * hin[src_e][f]
// Zero-pad trick: lanes past list end hold rs=0, rv=0 -> unconditional 4-edge
// groups (row 0 is valid memory, rv=0 nullifies). Depth-2 register pipeline.

// D=256: one wave per node, lane holds float4. EPI 0 plain, 1 (+bias,BN,ReLU)
template <int EPI>
__global__ __launch_bounds__(256) void agg256_kernel(
    const float* __restrict__ hin, float* __restrict__ hout,
    const int* __restrict__ off, const int* __restrict__ src,
    const float* __restrict__ val, const float* __restrict__ dinv,
    const float* __restrict__ bias, const float* __restrict__ g,
    const float* __restrict__ be, int n) {
  const int lane = threadIdx.x & 63;
  const int c = blockIdx.x * 4 + (threadIdx.x >> 6);
  if (c >= n) return;  // c uniform per wave: whole wave exits
  const int f4 = lane * 4;
  const int e0 = off[c], e1 = off[c + 1];
  const float di = dinv[c];
  const float s2 = di * di;
  float4 self = *(const float4*)&hin[(size_t)c * 256 + f4];
  float4 acc = make_float4(self.x * s2, self.y * s2, self.z * s2, self.w * s2);

  for (int base = e0; base < e1; base += 64) {
    int idx = base + lane;
    int rs = 0; float rv = 0.0f;
    if (idx < e1) { rs = src[idx]; rv = val[idx]; }
    const int m = min(64, e1 - base);
    const int nG = (m + 3) >> 2;  // wave-uniform

    float4 A0, A1, A2, A3, B0, B1, B2, B3;
    float va0, va1, va2, va3, vb0, vb1, vb2, vb3;

#define AGG256_PF(gidx, H0, H1, H2, H3, V0, V1, V2, V3)                      \
    {                                                                        \
      int e_ = (gidx) * 4;                                                   \
      int s0_ = __shfl(rs, e_);     V0 = __shfl(rv, e_);                     \
      int s1_ = __shfl(rs, e_ + 1); V1 = __shfl(rv, e_ + 1);                 \
      int s2_ = __shfl(rs, e_ + 2); V2 = __shfl(rv, e_ + 2);                 \
      int s3_ = __shfl(rs, e_ + 3); V3 = __shfl(rv, e_ + 3);                 \
      H0 = *(const float4*)&hin[(size_t)s0_ * 256 + f4];                     \
      H1 = *(const float4*)&hin[(size_t)s1_ * 256 + f4];                     \
      H2 = *(const float4*)&hin[(size_t)s2_ * 256 + f4];                     \
      H3 = *(const float4*)&hin[(size_t)s3_ * 256 + f4];                     \
    }
#define AGG256_FMA(H0, H1, H2, H3, V0, V1, V2, V3)                           \
    {                                                                        \
      acc.x += V0 * H0.x + V1 * H1.x + V2 * H2.x + V3 * H3.x;                \
      acc.y += V0 * H0.y + V1 * H1.y + V2 * H2.y + V3 * H3.y;                \
      acc.z += V0 * H0.z + V1 * H1.z + V2 * H2.z + V3 * H3.z;                \
      acc.w += V0 * H0.w + V1 * H1.w + V2 * H2.w + V3 * H3.w;                \
    }

    AGG256_PF(0, A0, A1, A2, A3, va0, va1, va2, va3);
    int gg = 0;
    for (; gg + 2 <= nG; gg += 2) {
      if (gg + 1 < nG) AGG256_PF(gg + 1, B0, B1, B2, B3, vb0, vb1, vb2, vb3);
      AGG256_FMA(A0, A1, A2, A3, va0, va1, va2, va3);
      if (gg + 2 < nG) AGG256_PF(gg + 2, A0, A1, A2, A3, va0, va1, va2, va3);
      AGG256_FMA(B0, B1, B2, B3, vb0, vb1, vb2, vb3);
    }
    if (gg < nG) AGG256_FMA(A0, A1, A2, A3, va0, va1, va2, va3);
#undef AGG256_PF
#undef AGG256_FMA
  }

  if (EPI == 1) {
    const float bns = rsqrtf(1.0f + GCN_BN_EPS);
    float4 bi = *(const float4*)&bias[f4];
    float4 gi = *(const float4*)&g[f4];
    float4 bei = *(const float4*)&be[f4];
    acc.x = fmaxf((acc.x + bi.x) * gi.x * bns + bei.x, 0.0f);
    acc.y = fmaxf((acc.y + bi.y) * gi.y * bns + bei.y, 0.0f);
    acc.z = fmaxf((acc.z + bi.z) * gi.z * bns + bei.z, 0.0f);
    acc.w = fmaxf((acc.w + bi.w) * gi.w * bns + bei.w, 0.0f);
  }
  *(float4*)&hout[(size_t)c * 256 + f4] = acc;
}

// D=128: TWO nodes per wave (half-wave x float4 covers 128 floats).
// EPI 0 plain, 2 (+bias, log_softmax over the 128 row)
template <int EPI>
__global__ __launch_bounds__(256) void agg128_kernel(
    const float* __restrict__ hin, float* __restrict__ hout,
    const int* __restrict__ off, const int* __restrict__ src,
    const float* __restrict__ val, const float* __restrict__ dinv,
    const float* __restrict__ bias, int n) {
  const int lane = threadIdx.x & 63;
  const int sub = lane & 31;
  const int hbase = lane & 32;  // 0 or 32: this half's lane base
  const int c = blockIdx.x * 8 + (threadIdx.x >> 6) * 2 + (lane >> 5);
  const bool active = (c < n);
  const int f4 = sub * 4;

  int e0 = 0, e1 = 0;
  float di = 0.0f;
  float4 acc = make_float4(0.f, 0.f, 0.f, 0.f);
  if (active) {
    e0 = off[c]; e1 = off[c + 1];
    di = dinv[c];
    float s2 = di * di;
    float4 self = *(const float4*)&hin[(size_t)c * 128 + f4];
    acc = make_float4(self.x * s2, self.y * s2, self.z * s2, self.w * s2);
  }
  // wave-uniform chunk count = max over the two halves
  int nch = (e1 - e0 + 31) >> 5;
  nch = max(nch, __shfl(nch, lane ^ 32));

  for (int ch = 0; ch < nch; ++ch) {
    int idx = e0 + ch * 32 + sub;
    int rs = 0; float rv = 0.0f;
    if (active && idx < e1) { rs = src[idx]; rv = val[idx]; }
    int m = e1 - (e0 + ch * 32);
    m = m < 0 ? 0 : (m > 32 ? 32 : m);
    int mMax = max(m, __shfl(m, lane ^ 32));
    const int nG = (mMax + 3) >> 2;  // wave-uniform; padded lanes contribute 0

    float4 A0, A1, A2, A3, B0, B1, B2, B3;
    float va0, va1, va2, va3, vb0, vb1, vb2, vb3;

#define AGG128_PF(gidx, H0, H1, H2, H3, V0, V1, V2, V3)                      \
    {                                                                        \
      int e_ = hbase + (gidx) * 4;                                           \
      int s0_ = __shfl(rs, e_);     V0 = __shfl(rv, e_);                     \
      int s1_ = __shfl(rs, e_ + 1); V1 = __shfl(rv, e_ + 1);                 \
      int s2_ = __shfl(rs, e_ + 2); V2 = __shfl(rv, e_ + 2);                 \
      int s3_ = __shfl(rs, e_ + 3); V3 = __shfl(rv, e_ + 3);                 \
      H0 = *(const float4*)&hin[(size_t)s0_ * 128 + f4];                     \
      H1 = *(const float4*)&hin[(size_t)s1_ * 128 + f4];                     \
      H2 = *(const float4*)&hin[(size_t)s2_ * 128 + f4];                     \
      H3 = *(const float4*)&hin[(size_t)s3_ * 128 + f4];                     \
    }
#define AGG128_FMA(H0, H1, H2, H3, V0, V1, V2, V3)                           \
    {                                                                        \
      acc.x += V0 * H0.x + V1 * H1.x + V2 * H2.x + V3 * H3.x;                \
      acc.y += V0 * H0.y + V1 * H1.y + V2 * H2.y + V3 * H3.y;                \
      acc.z += V0 * H0.z + V1 * H1.z + V2 * H2.z + V3 * H3.z;                \
      acc.w += V0 * H0.w + V1 * H1.w + V2 * H2.w + V3 * H3.w;                \
    }

    AGG128_PF(0, A0, A1, A2, A3, va0, va1, va2, va3);
    int gg = 0;
    for (; gg + 2 <= nG; gg += 2) {
      if (gg + 1 < nG) AGG128_PF(gg + 1, B0, B1, B2, B3, vb0, vb1, vb2, vb3);
      AGG128_FMA(A0, A1, A2, A3, va0, va1, va2, va3);
      if (gg + 2 < nG) AGG128_PF(gg + 2, A0, A1, A2, A3, va0, va1, va2, va3);
      AGG128_FMA(B0, B1, B2, B3, vb0, vb1, vb2, vb3);
    }
    if (gg < nG) AGG128_FMA(A0, A1, A2, A3, va0, va1, va2, va3);
#undef AGG128_PF
#undef AGG128_FMA
  }

  if (EPI == 0) {
    if (active) *(float4*)&hout[(size_t)c * 128 + f4] = acc;
  } else {
    float4 bi = active ? *(const float4*)&bias[f4] : make_float4(0.f, 0.f, 0.f, 0.f);
    float tx = acc.x + bi.x, ty = acc.y + bi.y, tz = acc.z + bi.z, tw = acc.w + bi.w;
    float mx = fmaxf(fmaxf(tx, ty), fmaxf(tz, tw));
#pragma unroll
    for (int s = 1; s < 32; s <<= 1) mx = fmaxf(mx, __shfl_xor(mx, s, 64));
    float ex = expf(tx - mx) + expf(ty - mx) + expf(tz - mx) + expf(tw - mx);
#pragma unroll
    for (int s = 1; s < 32; s <<= 1) ex += __shfl_xor(ex, s, 64);
    float lse = logf(ex) + mx;
    if (active) {
      float4 res = make_float4(tx - lse, ty - lse, tz - lse, tw - lse);
      *(float4*)&hout[(size_t)c * 128 + f4] = res;
    }
  }
}

// ---------------------------------------------------------------- fp32 GEMM
// C[M,Nc] = A[M,K] @ W[K,Nc]; tile 128x128, BK=32, 256 thr, 8x8/thread.
// epi 0: plain store; epi 1: relu((acc+bias)*g*rsqrt(1+eps)+be)
#define GB_M 128
#define GB_N 128
#define GB_K 32

__global__ __launch_bounds__(256, 2) void gemm_kernel(
    const float* __restrict__ A, const float* __restrict__ W,
    float* __restrict__ C, int M, int K, int Nc, int epi,
    const float* __restrict__ bias, const float* __restrict__ g,
    const float* __restrict__ be) {
  __shared__ float As[GB_K][132];   // transposed A tile, pad 128->132 (16B-aligned rows)
  __shared__ float Ws[GB_K][GB_N];
  const int tid = threadIdx.x;
  const int tx = tid & 15;   // col group
  const int ty = tid >> 4;   // row group
  const int row0 = blockIdx.y * GB_M;
  const int col0 = blockIdx.x * GB_N;

  float acc[2][4][2][4];  // [i4][i][j4][j]
#pragma unroll
  for (int a = 0; a < 2; ++a)
#pragma unroll
    for (int b = 0; b < 4; ++b)
#pragma unroll
      for (int cc = 0; cc < 2; ++cc)
#pragma unroll
        for (int d = 0; d < 4; ++d) acc[a][b][cc][d] = 0.0f;

  const int kq = tid & 7;         // A-stage k quad
  const int rl = tid >> 3;        // A-stage row 0..31
  const int wc4 = (tid & 31) * 4; // W-stage col
  const int wkr = tid >> 5;       // W-stage k row 0..7

  for (int k0 = 0; k0 < K; k0 += GB_K) {
#pragma unroll
    for (int p = 0; p < 4; ++p) {
      int r = rl + 32 * p;
      int grow = row0 + r;
      float4 v = make_float4(0.f, 0.f, 0.f, 0.f);
      if (grow < M) v = *(const float4*)&A[(size_t)grow * K + k0 + kq * 4];
      As[kq * 4 + 0][r] = v.x;
      As[kq * 4 + 1][r] = v.y;
      As[kq * 4 + 2][r] = v.z;
      As[kq * 4 + 3][r] = v.w;
    }
#pragma unroll
    for (int p = 0; p < 4; ++p) {
      int kk = wkr + 8 * p;
      *(float4*)&Ws[kk][wc4] = *(const float4*)&W[(size_t)(k0 + kk) * Nc + col0 + wc4];
    }
    __syncthreads();
#pragma unroll
    for (int kk = 0; kk < GB_K; ++kk) {
      float4 a0 = *(const float4*)&As[kk][ty * 4];
      float4 a1 = *(const float4*)&As[kk][ty * 4 + 64];
      float4 w0 = *(const float4*)&Ws[kk][tx * 4];
      float4 w1 = *(const float4*)&Ws[kk][tx * 4 + 64];
      float av[2][4] = {{a0.x, a0.y, a0.z, a0.w}, {a1.x, a1.y, a1.z, a1.w}};
      float wv[2][4] = {{w0.x, w0.y, w0.z, w0.w}, {w1.x, w1.y, w1.z, w1.w}};
#pragma unroll
      for (int i4 = 0; i4 < 2; ++i4)
#pragma unroll
        for (int i = 0; i < 4; ++i) {
          float a = av[i4][i];
#pragma unroll
          for (int j4 = 0; j4 < 2; ++j4)
#pragma unroll
            for (int j = 0; j < 4; ++j) acc[i4][i][j4][j] += a * wv[j4][j];
        }
    }
    __syncthreads();
  }

  const float bnscale = rsqrtf(1.0f + GCN_BN_EPS);
  float4 bi[2], gi[2], bei[2];
  if (epi == 1) {
#pragma unroll
    for (int j4 = 0; j4 < 2; ++j4) {
      int c = col0 + j4 * 64 + tx * 4;
      bi[j4] = *(const float4*)&bias[c];
      gi[j4] = *(const float4*)&g[c];
      bei[j4] = *(const float4*)&be[c];
    }
  }
#pragma unroll
  for (int i4 = 0; i4 < 2; ++i4)
#pragma unroll
    for (int i = 0; i < 4; ++i) {
      int r = row0 + i4 * 64 + ty * 4 + i;
      if (r >= M) continue;
#pragma unroll
      for (int j4 = 0; j4 < 2; ++j4) {
        int c = col0 + j4 * 64 + tx * 4;
        float4 res = make_float4(acc[i4][i][j4][0], acc[i4][i][j4][1],
                                 acc[i4][i][j4][2], acc[i4][i][j4][3]);
        if (epi == 1) {
          res.x = fmaxf((res.x + bi[j4].x) * gi[j4].x * bnscale + bei[j4].x, 0.f);
          res.y = fmaxf((res.y + bi[j4].y) * gi[j4].y * bnscale + bei[j4].y, 0.f);
          res.z = fmaxf((res.z + bi[j4].z) * gi[j4].z * bnscale + bei[j4].z, 0.f);
          res.w = fmaxf((res.w + bi[j4].w) * gi[j4].w * bnscale + bei[j4].w, 0.f);
        }
        *(float4*)&C[(size_t)r * Nc + c] = res;
      }
    }
}

// ---------------------------------------------------------------- launch

static inline char* carve(char*& p, size_t bytes) {
  char* r = p;
  p += (bytes + 255) & ~(size_t)255;
  return r;
}

extern "C" void kernel_launch(void* const* d_in, const int* in_sizes, int n_in,
                              void* d_out, int out_size, void* d_ws, size_t ws_size,
                              hipStream_t stream) {
  const int N = in_sizes[0] / 128;
  const int E = in_sizes[2];

  const float* x  = (const float*)d_in[0];
  const int*   ei = (const int*)d_in[1];
  const float* ew = (const float*)d_in[2];
  const float* W0 = (const float*)d_in[3];
  const float* b0 = (const float*)d_in[4];
  const float* W1 = (const float*)d_in[5];
  const float* b1 = (const float*)d_in[6];
  const float* Wl = (const float*)d_in[7];
  const float* bl = (const float*)d_in[8];
  const float* g0 = (const float*)d_in[9];
  const float* be0 = (const float*)d_in[10];
  const float* g1 = (const float*)d_in[11];
  const float* be1 = (const float*)d_in[12];
  float* out = (float*)d_out;

  char* p = (char*)d_ws;
  float* deg     = (float*)carve(p, (size_t)N * 4);
  float* dinv    = (float*)carve(p, (size_t)N * 4);
  int*   cnt     = (int*)carve(p, (size_t)N * 4);
  int*   cursor  = (int*)carve(p, (size_t)N * 4);
  int*   off     = (int*)carve(p, (size_t)(N + 1) * 4);
  int*   flag    = (int*)carve(p, 256);
  int*   bsum    = (int*)carve(p, 1024 * 4);
  int*   row_    = (int*)carve(p, (size_t)E * 4);
  int*   col_    = (int*)carve(p, (size_t)E * 4);
  int*   csr_src = (int*)carve(p, (size_t)E * 4);
  float* csr_val = (float*)carve(p, (size_t)E * 4);
  float* bufA    = (float*)carve(p, (size_t)N * 256 * 4);
  float* bufB    = (float*)carve(p, (size_t)N * 256 * 4);

  const int TB = 256;
  const int gN = (N + TB - 1) / TB;   // 196
  const int gE = (E + TB - 1) / TB;
  const int gW4 = (N + 3) / 4;        // agg256: 4 nodes (waves) per block
  const int gW8 = (N + 7) / 8;        // agg128: 8 nodes (2 per wave) per block

  init_detect_kernel<<<gN, TB, 0, stream>>>(deg, cnt, ei, flag, N);
  decode_deg_kernel<<<gE, TB, 0, stream>>>(ei, ew, flag, row_, col_, deg, cnt, E);
  scan1_kernel<<<gN, TB, 0, stream>>>(cnt, deg, dinv, bsum, N);
  scan2_kernel<<<1, 1024, 0, stream>>>(bsum, gN, off, N, E);
  scan3_kernel<<<gN, TB, 0, stream>>>(cnt, bsum, off, cursor, N);
  fill_kernel<<<gE, TB, 0, stream>>>(row_, col_, ew, dinv, cursor, csr_src, csr_val, E);

  // layer 0: agg(x,128) -> bufA; GEMM0 + b0 + BN0 + ReLU -> bufB[N,256]
  agg128_kernel<0><<<gW8, 256, 0, stream>>>(x, bufA, off, csr_src, csr_val, dinv,
                                            nullptr, N);
  {
    dim3 grid(256 / GB_N, (N + GB_M - 1) / GB_M);
    gemm_kernel<<<grid, 256, 0, stream>>>(bufA, W0, bufB, N, 128, 256, 1, b0, g0, be0);
  }
  // layer 1: GEMM1 -> bufA[N,256]; agg + b1 + BN1 + ReLU -> bufB[N,256]
  {
    dim3 grid(256 / GB_N, (N + GB_M - 1) / GB_M);
    gemm_kernel<<<grid, 256, 0, stream>>>(bufB, W1, bufA, N, 256, 256, 0,
                                          nullptr, nullptr, nullptr);
  }
  agg256_kernel<1><<<gW4, 256, 0, stream>>>(bufA, bufB, off, csr_src, csr_val, dinv,
                                            b1, g1, be1, N);
  // layer 2: GEMM2 -> bufA[N,128]; agg + bl + log_softmax -> out
  {
    dim3 grid(128 / GB_N, (N + GB_M - 1) / GB_M);
    gemm_kernel<<<grid, 256, 0, stream>>>(bufB, Wl, bufA, N, 256, 128, 0,
                                          nullptr, nullptr, nullptr);
  }
  agg128_kernel<2><<<gW8, 256, 0, stream>>>(bufA, out, off, csr_src, csr_val, dinv,
                                            bl, N);
}

// Round 5
// 525.632 us; speedup vs baseline: 1.3650x; 1.2621x over previous
//
#include <hip/hip_runtime.h>
#include <cstddef>
#include <cstdint>

// GCN 3-layer forward, MI355X.
// R5: bf16 feature storage (fp32 accumulate) halves the compulsory per-XCD L2
// fill that bounds aggregation (R4: FETCH 400MB = 8 XCD x 51MB at 3.7 TB/s);
// GEMMs moved to MFMA 16x16x32 bf16 (one wave per 16 rows, W^T L2-resident,
// no LDS/barriers). Preprocessing (CSC build) unchanged, fp32 norm values.

#define GCN_BN_EPS 1e-5f

typedef short v8bf __attribute__((ext_vector_type(8)));
typedef float v4f __attribute__((ext_vector_type(4)));

// ---------------------------------------------------------------- bf16 utils

__device__ __forceinline__ float4 unpack_bf4(uint2 u) {
  float4 r;
  r.x = __uint_as_float(u.x << 16);
  r.y = __uint_as_float(u.x & 0xffff0000u);
  r.z = __uint_as_float(u.y << 16);
  r.w = __uint_as_float(u.y & 0xffff0000u);
  return r;
}
__device__ __forceinline__ uint16_t f2bf(float f) {
  uint32_t u = __float_as_uint(f);
  return (uint16_t)((u + 0x7fffu + ((u >> 16) & 1u)) >> 16);  // RNE
}
__device__ __forceinline__ uint2 pack_bf4(float4 v) {
  uint2 r;
  r.x = (uint32_t)f2bf(v.x) | ((uint32_t)f2bf(v.y) << 16);
  r.y = (uint32_t)f2bf(v.z) | ((uint32_t)f2bf(v.w) << 16);
  return r;
}

// ---------------------------------------------------------------- preprocess

__global__ void init_detect_kernel(float* __restrict__ deg, int* __restrict__ cnt,
                                   const int* __restrict__ ei, int* __restrict__ flag,
                                   int n) {
  int i = blockIdx.x * blockDim.x + threadIdx.x;
  if (i < n) { deg[i] = 1.0f; cnt[i] = 0; }  // deg starts at 1.0 (self-loop w=1)
  if (blockIdx.x == 0 && threadIdx.x == 0) {
    int nz = 0;
    for (int k = 1; k < 64; k += 2) nz |= ei[k];
    *flag = (nz == 0) ? 1 : 0;  // 1 => int64 layout
  }
}

__global__ void decode_deg_kernel(const int* __restrict__ ei, const float* __restrict__ ew,
                                  const int* __restrict__ flag,
                                  int* __restrict__ row_, int* __restrict__ col_,
                                  float* __restrict__ deg, int* __restrict__ cnt, int E) {
  int e = blockIdx.x * blockDim.x + threadIdx.x;
  if (e >= E) return;
  int r, c;
  if (*flag) { r = ei[2 * e]; c = ei[2 * (E + e)]; }
  else       { r = ei[e];     c = ei[E + e]; }
  row_[e] = r; col_[e] = c;
  atomicAdd(&deg[c], ew[e]);
  atomicAdd(&cnt[c], 1);
}

__global__ __launch_bounds__(256) void scan1_kernel(const int* __restrict__ cnt,
                                                    const float* __restrict__ deg,
                                                    float* __restrict__ dinv,
                                                    int* __restrict__ bsum, int n) {
  __shared__ int ws[4];
  int i = blockIdx.x * 256 + threadIdx.x;
  int v = (i < n) ? cnt[i] : 0;
  if (i < n) dinv[i] = rsqrtf(deg[i]);
  int x = v;
#pragma unroll
  for (int s = 1; s < 64; s <<= 1) x += __shfl_xor(x, s, 64);
  if ((threadIdx.x & 63) == 0) ws[threadIdx.x >> 6] = x;
  __syncthreads();
  if (threadIdx.x == 0) bsum[blockIdx.x] = ws[0] + ws[1] + ws[2] + ws[3];
}

__global__ __launch_bounds__(1024) void scan2_kernel(int* __restrict__ bsum, int G,
                                                     int* __restrict__ off, int n, int E) {
  __shared__ int wsum[16], woff[16];
  int tid = threadIdx.x, lane = tid & 63, wv = tid >> 6;
  int v = (tid < G) ? bsum[tid] : 0;
  int x = v;
#pragma unroll
  for (int s = 1; s < 64; s <<= 1) { int t = __shfl_up(x, s, 64); if (lane >= s) x += t; }
  if (lane == 63) wsum[wv] = x;
  __syncthreads();
  if (wv == 0) {
    int wsv = (lane < 16) ? wsum[lane] : 0;
    int y = wsv;
#pragma unroll
    for (int s = 1; s < 16; s <<= 1) { int t = __shfl_up(y, s, 64); if (lane >= s) y += t; }
    if (lane < 16) woff[lane] = y - wsv;
  }
  __syncthreads();
  if (tid < G) bsum[tid] = x - v + woff[wv];
  if (tid == 0) off[n] = E;
}

__global__ __launch_bounds__(256) void scan3_kernel(const int* __restrict__ cnt,
                                                    const int* __restrict__ bsum,
                                                    int* __restrict__ off,
                                                    int* __restrict__ cursor, int n) {
  __shared__ int wsum[4], woff[4];
  int tid = threadIdx.x, lane = tid & 63, wv = tid >> 6;
  int i = blockIdx.x * 256 + tid;
  int v = (i < n) ? cnt[i] : 0;
  int x = v;
#pragma unroll
  for (int s = 1; s < 64; s <<= 1) { int t = __shfl_up(x, s, 64); if (lane >= s) x += t; }
  if (lane == 63) wsum[wv] = x;
  __syncthreads();
  if (tid == 0) { int r = 0; for (int k = 0; k < 4; ++k) { woff[k] = r; r += wsum[k]; } }
  __syncthreads();
  if (i < n) {
    int excl = x - v + woff[wv] + bsum[blockIdx.x];
    off[i] = excl;
    cursor[i] = excl;
  }
}

__global__ void fill_kernel(const int* __restrict__ row_, const int* __restrict__ col_,
                            const float* __restrict__ ew, const float* __restrict__ dinv,
                            int* __restrict__ cursor,
                            int* __restrict__ csr_src, float* __restrict__ csr_val, int E) {
  int e = blockIdx.x * blockDim.x + threadIdx.x;
  if (e >= E) return;
  int r = row_[e], c = col_[e];
  int p = atomicAdd(&cursor[c], 1);
  csr_src[p] = r;
  csr_val[p] = dinv[r] * ew[e] * dinv[c];
}

// ---------------------------------------------------------------- conversions

// fp32 -> bf16, vectorized (n4 = count/4)
__global__ void conv_x_kernel(const float* __restrict__ x, uint16_t* __restrict__ xb,
                              int n4) {
  int i = blockIdx.x * blockDim.x + threadIdx.x;
  if (i >= n4) return;
  float4 v = *(const float4*)&x[(size_t)i * 4];
  *(uint2*)&xb[(size_t)i * 4] = pack_bf4(v);
}

// W[K][N] fp32 -> WT[N][K] bf16
__global__ void conv_wt_kernel(const float* __restrict__ W, uint16_t* __restrict__ WT,
                               int K, int Nc) {
  int i = blockIdx.x * blockDim.x + threadIdx.x;
  if (i >= K * Nc) return;
  int n = i / K, k = i - n * K;
  WT[i] = f2bf(W[(size_t)k * Nc + n]);
}

// ---------------------------------------------------------------- aggregation
// out[c][f] = dinv[c]^2 * hin[c][f] + sum_e val_e * hin[src_e][f]  (bf16 rows)

// D=256 bf16: one wave per node, lane holds 4 feats (8B). EPI 0 plain, 1 BN+ReLU
template <int EPI>
__global__ __launch_bounds__(256) void agg256_kernel(
    const uint16_t* __restrict__ hin, uint16_t* __restrict__ hout,
    const int* __restrict__ off, const int* __restrict__ src,
    const float* __restrict__ val, const float* __restrict__ dinv,
    const float* __restrict__ bias, const float* __restrict__ g,
    const float* __restrict__ be, int n) {
  const int lane = threadIdx.x & 63;
  const int c = blockIdx.x * 4 + (threadIdx.x >> 6);
  if (c >= n) return;
  const int f = lane * 4;
  const int e0 = off[c], e1 = off[c + 1];
  const float di = dinv[c];
  const float s2 = di * di;
  float4 self = unpack_bf4(*(const uint2*)&hin[(size_t)c * 256 + f]);
  float4 acc = make_float4(self.x * s2, self.y * s2, self.z * s2, self.w * s2);

  for (int base = e0; base < e1; base += 64) {
    int idx = base + lane;
    int rs = 0; float rv = 0.0f;                 // zero-pad: row 0 x weight 0
    if (idx < e1) { rs = src[idx]; rv = val[idx]; }
    const int m = min(64, e1 - base);
    const int nG = (m + 3) >> 2;
    for (int gI = 0; gI < nG; ++gI) {
      int e_ = gI * 4;
      int s0 = __shfl(rs, e_);     float v0 = __shfl(rv, e_);
      int s1 = __shfl(rs, e_ + 1); float v1 = __shfl(rv, e_ + 1);
      int sB = __shfl(rs, e_ + 2); float v2 = __shfl(rv, e_ + 2);
      int s3 = __shfl(rs, e_ + 3); float v3 = __shfl(rv, e_ + 3);
      float4 h0 = unpack_bf4(*(const uint2*)&hin[(size_t)s0 * 256 + f]);
      float4 h1 = unpack_bf4(*(const uint2*)&hin[(size_t)s1 * 256 + f]);
      float4 h2 = unpack_bf4(*(const uint2*)&hin[(size_t)sB * 256 + f]);
      float4 h3 = unpack_bf4(*(const uint2*)&hin[(size_t)s3 * 256 + f]);
      acc.x += v0 * h0.x + v1 * h1.x + v2 * h2.x + v3 * h3.x;
      acc.y += v0 * h0.y + v1 * h1.y + v2 * h2.y + v3 * h3.y;
      acc.z += v0 * h0.z + v1 * h1.z + v2 * h2.z + v3 * h3.z;
      acc.w += v0 * h0.w + v1 * h1.w + v2 * h2.w + v3 * h3.w;
    }
  }

  if (EPI == 1) {
    const float bns = rsqrtf(1.0f + GCN_BN_EPS);
    float4 bi = *(const float4*)&bias[f];
    float4 gi = *(const float4*)&g[f];
    float4 bei = *(const float4*)&be[f];
    acc.x = fmaxf((acc.x + bi.x) * gi.x * bns + bei.x, 0.0f);
    acc.y = fmaxf((acc.y + bi.y) * gi.y * bns + bei.y, 0.0f);
    acc.z = fmaxf((acc.z + bi.z) * gi.z * bns + bei.z, 0.0f);
    acc.w = fmaxf((acc.w + bi.w) * gi.w * bns + bei.w, 0.0f);
  }
  *(uint2*)&hout[(size_t)c * 256 + f] = pack_bf4(acc);
}

// D=128 bf16: two nodes per wave (half-wave x 4 feats, 8B/lane).
// EPI 0: plain bf16 store. EPI 2: +bias, log_softmax -> fp32 out.
template <int EPI>
__global__ __launch_bounds__(256) void agg128_kernel(
    const uint16_t* __restrict__ hin, void* __restrict__ hout_,
    const int* __restrict__ off, const int* __restrict__ src,
    const float* __restrict__ val, const float* __restrict__ dinv,
    const float* __restrict__ bias, int n) {
  const int lane = threadIdx.x & 63;
  const int sub = lane & 31;
  const int hbase = lane & 32;
  const int c = blockIdx.x * 8 + (threadIdx.x >> 6) * 2 + (lane >> 5);
  const bool active = (c < n);
  const int f = sub * 4;

  int e0 = 0, e1 = 0;
  float4 acc = make_float4(0.f, 0.f, 0.f, 0.f);
  if (active) {
    e0 = off[c]; e1 = off[c + 1];
    float di = dinv[c];
    float s2 = di * di;
    float4 self = unpack_bf4(*(const uint2*)&hin[(size_t)c * 128 + f]);
    acc = make_float4(self.x * s2, self.y * s2, self.z * s2, self.w * s2);
  }
  int nch = (e1 - e0 + 31) >> 5;
  nch = max(nch, __shfl(nch, lane ^ 32));

  for (int ch = 0; ch < nch; ++ch) {
    int idx = e0 + ch * 32 + sub;
    int rs = 0; float rv = 0.0f;
    if (active && idx < e1) { rs = src[idx]; rv = val[idx]; }
    int m = e1 - (e0 + ch * 32);
    m = m < 0 ? 0 : (m > 32 ? 32 : m);
    int mMax = max(m, __shfl(m, lane ^ 32));
    const int nG = (mMax + 3) >> 2;
    for (int gI = 0; gI < nG; ++gI) {
      int e_ = hbase + gI * 4;
      int s0 = __shfl(rs, e_);     float v0 = __shfl(rv, e_);
      int s1 = __shfl(rs, e_ + 1); float v1 = __shfl(rv, e_ + 1);
      int sB = __shfl(rs, e_ + 2); float v2 = __shfl(rv, e_ + 2);
      int s3 = __shfl(rs, e_ + 3); float v3 = __shfl(rv, e_ + 3);
      float4 h0 = unpack_bf4(*(const uint2*)&hin[(size_t)s0 * 128 + f]);
      float4 h1 = unpack_bf4(*(const uint2*)&hin[(size_t)s1 * 128 + f]);
      float4 h2 = unpack_bf4(*(const uint2*)&hin[(size_t)sB * 128 + f]);
      float4 h3 = unpack_bf4(*(const uint2*)&hin[(size_t)s3 * 128 + f]);
      acc.x += v0 * h0.x + v1 * h1.x + v2 * h2.x + v3 * h3.x;
      acc.y += v0 * h0.y + v1 * h1.y + v2 * h2.y + v3 * h3.y;
      acc.z += v0 * h0.z + v1 * h1.z + v2 * h2.z + v3 * h3.z;
      acc.w += v0 * h0.w + v1 * h1.w + v2 * h2.w + v3 * h3.w;
    }
  }

  if (EPI == 0) {
    uint16_t* hout = (uint16_t*)hout_;
    if (active) *(uint2*)&hout[(size_t)c * 128 + f] = pack_bf4(acc);
  } else {
    float* hout = (float*)hout_;
    float4 bi = active ? *(const float4*)&bias[f] : make_float4(0.f, 0.f, 0.f, 0.f);
    float tx = acc.x + bi.x, ty = acc.y + bi.y, tz = acc.z + bi.z, tw = acc.w + bi.w;
    float mx = fmaxf(fmaxf(tx, ty), fmaxf(tz, tw));
#pragma unroll
    for (int s = 1; s < 32; s <<= 1) mx = fmaxf(mx, __shfl_xor(mx, s, 64));
    float ex = expf(tx - mx) + expf(ty - mx) + expf(tz - mx) + expf(tw - mx);
#pragma unroll
    for (int s = 1; s < 32; s <<= 1) ex += __shfl_xor(ex, s, 64);
    float lse = logf(ex) + mx;
    if (active) {
      float4 res = make_float4(tx - lse, ty - lse, tz - lse, tw - lse);
      *(float4*)&hout[(size_t)c * 128 + f] = res;
    }
  }
}

// ---------------------------------------------------------------- MFMA GEMM
// C[M,NC] = A[M,K] @ W[K,NC], A bf16 [M][K], WT bf16 [NC][K] (L2-resident).
// One wave per 16 rows x full NC. mfma_f32_16x16x32_bf16:
//   A-frag: lane holds A[m=lane&15][k=quad*8+j] (16B contiguous)
//   B-frag: lane holds W[k=quad*8+j][n=lane&15] = WT[n][k..k+8]
//   C/D:    col=lane&15, row=quad*4+reg
// EPI 0: plain bf16 store; EPI 1: relu((acc+bias)*g*bns+be) -> bf16
template <int K, int NC, int EPI>
__global__ __launch_bounds__(256) void mfma_gemm_kernel(
    const uint16_t* __restrict__ A, const uint16_t* __restrict__ WT,
    uint16_t* __restrict__ Cb, int M,
    const float* __restrict__ bias, const float* __restrict__ g,
    const float* __restrict__ be) {
  constexpr int NT = NC / 16;
  const int lane = threadIdx.x & 63;
  const int wave = threadIdx.x >> 6;
  const int quad = lane >> 4;
  const int l16 = lane & 15;
  const int row0 = blockIdx.x * 64 + wave * 16;

  v4f acc[NT];
#pragma unroll
  for (int nt = 0; nt < NT; ++nt) acc[nt] = (v4f){0.f, 0.f, 0.f, 0.f};

  int arow = row0 + l16;
  if (arow >= M) arow = M - 1;                 // clamp; stores are guarded
  const uint16_t* Ap = A + (size_t)arow * K + quad * 8;

#pragma unroll
  for (int k0 = 0; k0 < K; k0 += 32) {
    v8bf a = *(const v8bf*)(Ap + k0);
#pragma unroll
    for (int nt = 0; nt < NT; ++nt) {
      v8bf b = *(const v8bf*)(WT + (size_t)(nt * 16 + l16) * K + k0 + quad * 8);
      acc[nt] = __builtin_amdgcn_mfma_f32_16x16x32_bf16(a, b, acc[nt], 0, 0, 0);
    }
  }

  const float bns = rsqrtf(1.0f + GCN_BN_EPS);
#pragma unroll
  for (int nt = 0; nt < NT; ++nt) {
    const int col = nt * 16 + l16;
    float sc = 1.0f, o1 = 0.0f, o2 = 0.0f;
    if (EPI == 1) { sc = g[col] * bns; o1 = bias[col]; o2 = be[col]; }
#pragma unroll
    for (int r = 0; r < 4; ++r) {
      int row = row0 + quad * 4 + r;
      if (row < M) {
        float v = acc[nt][r];
        if (EPI == 1) v = fmaxf((v + o1) * sc + o2, 0.0f);
        Cb[(size_t)row * NC + col] = f2bf(v);
      }
    }
  }
}

// ---------------------------------------------------------------- launch

static inline char* carve(char*& p, size_t bytes) {
  char* r = p;
  p += (bytes + 255) & ~(size_t)255;
  return r;
}

extern "C" void kernel_launch(void* const* d_in, const int* in_sizes, int n_in,
                              void* d_out, int out_size, void* d_ws, size_t ws_size,
                              hipStream_t stream) {
  const int N = in_sizes[0] / 128;
  const int E = in_sizes[2];

  const float* x  = (const float*)d_in[0];
  const int*   ei = (const int*)d_in[1];
  const float* ew = (const float*)d_in[2];
  const float* W0 = (const float*)d_in[3];
  const float* b0 = (const float*)d_in[4];
  const float* W1 = (const float*)d_in[5];
  const float* b1 = (const float*)d_in[6];
  const float* Wl = (const float*)d_in[7];
  const float* bl = (const float*)d_in[8];
  const float* g0 = (const float*)d_in[9];
  const float* be0 = (const float*)d_in[10];
  const float* g1 = (const float*)d_in[11];
  const float* be1 = (const float*)d_in[12];
  float* out = (float*)d_out;

  char* p = (char*)d_ws;
  float*    deg     = (float*)carve(p, (size_t)N * 4);
  float*    dinv    = (float*)carve(p, (size_t)N * 4);
  int*      cnt     = (int*)carve(p, (size_t)N * 4);
  int*      cursor  = (int*)carve(p, (size_t)N * 4);
  int*      off     = (int*)carve(p, (size_t)(N + 1) * 4);
  int*      flag    = (int*)carve(p, 256);
  int*      bsum    = (int*)carve(p, 1024 * 4);
  int*      row_    = (int*)carve(p, (size_t)E * 4);
  int*      col_    = (int*)carve(p, (size_t)E * 4);
  int*      csr_src = (int*)carve(p, (size_t)E * 4);
  float*    csr_val = (float*)carve(p, (size_t)E * 4);
  uint16_t* xb16    = (uint16_t*)carve(p, (size_t)N * 128 * 2);
  uint16_t* bufR    = (uint16_t*)carve(p, (size_t)N * 128 * 2);
  uint16_t* bufP    = (uint16_t*)carve(p, (size_t)N * 256 * 2);
  uint16_t* bufQ    = (uint16_t*)carve(p, (size_t)N * 256 * 2);
  uint16_t* W0t     = (uint16_t*)carve(p, (size_t)128 * 256 * 2);
  uint16_t* W1t     = (uint16_t*)carve(p, (size_t)256 * 256 * 2);
  uint16_t* Wlt     = (uint16_t*)carve(p, (size_t)256 * 128 * 2);

  const int TB = 256;
  const int gN = (N + TB - 1) / TB;
  const int gE = (E + TB - 1) / TB;
  const int gW4 = (N + 3) / 4;   // agg256: 4 nodes/block
  const int gW8 = (N + 7) / 8;   // agg128: 8 nodes/block
  const int gG = (N + 63) / 64;  // gemm: 64 rows/block

  // preprocessing + conversions
  init_detect_kernel<<<gN, TB, 0, stream>>>(deg, cnt, ei, flag, N);
  decode_deg_kernel<<<gE, TB, 0, stream>>>(ei, ew, flag, row_, col_, deg, cnt, E);
  scan1_kernel<<<gN, TB, 0, stream>>>(cnt, deg, dinv, bsum, N);
  scan2_kernel<<<1, 1024, 0, stream>>>(bsum, gN, off, N, E);
  scan3_kernel<<<gN, TB, 0, stream>>>(cnt, bsum, off, cursor, N);
  fill_kernel<<<gE, TB, 0, stream>>>(row_, col_, ew, dinv, cursor, csr_src, csr_val, E);
  conv_x_kernel<<<(N * 32 + TB - 1) / TB, TB, 0, stream>>>(x, xb16, N * 32);
  conv_wt_kernel<<<(128 * 256 + TB - 1) / TB, TB, 0, stream>>>(W0, W0t, 128, 256);
  conv_wt_kernel<<<(256 * 256 + TB - 1) / TB, TB, 0, stream>>>(W1, W1t, 256, 256);
  conv_wt_kernel<<<(256 * 128 + TB - 1) / TB, TB, 0, stream>>>(Wl, Wlt, 256, 128);

  // layer 0: agg(xb16,128) -> bufR; MFMA GEMM0 +BN0+ReLU -> bufP[N,256]
  agg128_kernel<0><<<gW8, 256, 0, stream>>>(xb16, bufR, off, csr_src, csr_val, dinv,
                                            nullptr, N);
  mfma_gemm_kernel<128, 256, 1><<<gG, 256, 0, stream>>>(bufR, W0t, bufP, N, b0, g0, be0);
  // layer 1: GEMM1 -> bufQ; agg256 +b1+BN1+ReLU -> bufP
  mfma_gemm_kernel<256, 256, 0><<<gG, 256, 0, stream>>>(bufP, W1t, bufQ, N,
                                                        nullptr, nullptr, nullptr);
  agg256_kernel<1><<<gW4, 256, 0, stream>>>(bufQ, bufP, off, csr_src, csr_val, dinv,
                                            b1, g1, be1, N);
  // layer 2: GEMM2 -> bufR; agg128 +bl+log_softmax -> out (fp32)
  mfma_gemm_kernel<256, 128, 0><<<gG, 256, 0, stream>>>(bufP, Wlt, bufR, N,
                                                        nullptr, nullptr, nullptr);
  agg128_kernel<2><<<gW8, 256, 0, stream>>>(bufR, out, off, csr_src, csr_val, dinv,
                                            bl, N);
}

// Round 6
// 433.448 us; speedup vs baseline: 1.6553x; 1.2127x over previous
//
#include <hip/hip_runtime.h>
#include <cstddef>
#include <cstdint>

// GCN 3-layer forward, MI355X.
// R6: B-stationary MFMA GEMM — each wave holds its 64-column B-fragments in
// registers (loaded once) and streams 16-row A-tiles with depth-2 prefetch;
// 4 waves/block share A rows (L1 reuse). R5's GEMM was latency-bound at 2.8%
// MfmaUtil because B-frags were re-fetched per tile with no VGPR headroom.
// Aggregation (bf16 gathers) and CSC preprocessing unchanged from R5.

#define GCN_BN_EPS 1e-5f

typedef short v8bf __attribute__((ext_vector_type(8)));
typedef float v4f __attribute__((ext_vector_type(4)));

// ---------------------------------------------------------------- bf16 utils

__device__ __forceinline__ float4 unpack_bf4(uint2 u) {
  float4 r;
  r.x = __uint_as_float(u.x << 16);
  r.y = __uint_as_float(u.x & 0xffff0000u);
  r.z = __uint_as_float(u.y << 16);
  r.w = __uint_as_float(u.y & 0xffff0000u);
  return r;
}
__device__ __forceinline__ uint16_t f2bf(float f) {
  uint32_t u = __float_as_uint(f);
  return (uint16_t)((u + 0x7fffu + ((u >> 16) & 1u)) >> 16);  // RNE
}
__device__ __forceinline__ uint2 pack_bf4(float4 v) {
  uint2 r;
  r.x = (uint32_t)f2bf(v.x) | ((uint32_t)f2bf(v.y) << 16);
  r.y = (uint32_t)f2bf(v.z) | ((uint32_t)f2bf(v.w) << 16);
  return r;
}

// ---------------------------------------------------------------- preprocess

__global__ void init_detect_kernel(float* __restrict__ deg, int* __restrict__ cnt,
                                   const int* __restrict__ ei, int* __restrict__ flag,
                                   int n) {
  int i = blockIdx.x * blockDim.x + threadIdx.x;
  if (i < n) { deg[i] = 1.0f; cnt[i] = 0; }  // deg starts at 1.0 (self-loop w=1)
  if (blockIdx.x == 0 && threadIdx.x == 0) {
    int nz = 0;
    for (int k = 1; k < 64; k += 2) nz |= ei[k];
    *flag = (nz == 0) ? 1 : 0;  // 1 => int64 layout
  }
}

__global__ void decode_deg_kernel(const int* __restrict__ ei, const float* __restrict__ ew,
                                  const int* __restrict__ flag,
                                  int* __restrict__ row_, int* __restrict__ col_,
                                  float* __restrict__ deg, int* __restrict__ cnt, int E) {
  int e = blockIdx.x * blockDim.x + threadIdx.x;
  if (e >= E) return;
  int r, c;
  if (*flag) { r = ei[2 * e]; c = ei[2 * (E + e)]; }
  else       { r = ei[e];     c = ei[E + e]; }
  row_[e] = r; col_[e] = c;
  atomicAdd(&deg[c], ew[e]);
  atomicAdd(&cnt[c], 1);
}

__global__ __launch_bounds__(256) void scan1_kernel(const int* __restrict__ cnt,
                                                    const float* __restrict__ deg,
                                                    float* __restrict__ dinv,
                                                    int* __restrict__ bsum, int n) {
  __shared__ int ws[4];
  int i = blockIdx.x * 256 + threadIdx.x;
  int v = (i < n) ? cnt[i] : 0;
  if (i < n) dinv[i] = rsqrtf(deg[i]);
  int x = v;
#pragma unroll
  for (int s = 1; s < 64; s <<= 1) x += __shfl_xor(x, s, 64);
  if ((threadIdx.x & 63) == 0) ws[threadIdx.x >> 6] = x;
  __syncthreads();
  if (threadIdx.x == 0) bsum[blockIdx.x] = ws[0] + ws[1] + ws[2] + ws[3];
}

__global__ __launch_bounds__(1024) void scan2_kernel(int* __restrict__ bsum, int G,
                                                     int* __restrict__ off, int n, int E) {
  __shared__ int wsum[16], woff[16];
  int tid = threadIdx.x, lane = tid & 63, wv = tid >> 6;
  int v = (tid < G) ? bsum[tid] : 0;
  int x = v;
#pragma unroll
  for (int s = 1; s < 64; s <<= 1) { int t = __shfl_up(x, s, 64); if (lane >= s) x += t; }
  if (lane == 63) wsum[wv] = x;
  __syncthreads();
  if (wv == 0) {
    int wsv = (lane < 16) ? wsum[lane] : 0;
    int y = wsv;
#pragma unroll
    for (int s = 1; s < 16; s <<= 1) { int t = __shfl_up(y, s, 64); if (lane >= s) y += t; }
    if (lane < 16) woff[lane] = y - wsv;
  }
  __syncthreads();
  if (tid < G) bsum[tid] = x - v + woff[wv];
  if (tid == 0) off[n] = E;
}

__global__ __launch_bounds__(256) void scan3_kernel(const int* __restrict__ cnt,
                                                    const int* __restrict__ bsum,
                                                    int* __restrict__ off,
                                                    int* __restrict__ cursor, int n) {
  __shared__ int wsum[4], woff[4];
  int tid = threadIdx.x, lane = tid & 63, wv = tid >> 6;
  int i = blockIdx.x * 256 + tid;
  int v = (i < n) ? cnt[i] : 0;
  int x = v;
#pragma unroll
  for (int s = 1; s < 64; s <<= 1) { int t = __shfl_up(x, s, 64); if (lane >= s) x += t; }
  if (lane == 63) wsum[wv] = x;
  __syncthreads();
  if (tid == 0) { int r = 0; for (int k = 0; k < 4; ++k) { woff[k] = r; r += wsum[k]; } }
  __syncthreads();
  if (i < n) {
    int excl = x - v + woff[wv] + bsum[blockIdx.x];
    off[i] = excl;
    cursor[i] = excl;
  }
}

__global__ void fill_kernel(const int* __restrict__ row_, const int* __restrict__ col_,
                            const float* __restrict__ ew, const float* __restrict__ dinv,
                            int* __restrict__ cursor,
                            int* __restrict__ csr_src, float* __restrict__ csr_val, int E) {
  int e = blockIdx.x * blockDim.x + threadIdx.x;
  if (e >= E) return;
  int r = row_[e], c = col_[e];
  int p = atomicAdd(&cursor[c], 1);
  csr_src[p] = r;
  csr_val[p] = dinv[r] * ew[e] * dinv[c];
}

// ---------------------------------------------------------------- conversions

__global__ void conv_x_kernel(const float* __restrict__ x, uint16_t* __restrict__ xb,
                              int n4) {
  int i = blockIdx.x * blockDim.x + threadIdx.x;
  if (i >= n4) return;
  float4 v = *(const float4*)&x[(size_t)i * 4];
  *(uint2*)&xb[(size_t)i * 4] = pack_bf4(v);
}

// W[K][N] fp32 -> WT[N][K] bf16
__global__ void conv_wt_kernel(const float* __restrict__ W, uint16_t* __restrict__ WT,
                               int K, int Nc) {
  int i = blockIdx.x * blockDim.x + threadIdx.x;
  if (i >= K * Nc) return;
  int n = i / K, k = i - n * K;
  WT[i] = f2bf(W[(size_t)k * Nc + n]);
}

// ---------------------------------------------------------------- aggregation

// D=256 bf16: one wave per node, lane holds 4 feats (8B). EPI 0 plain, 1 BN+ReLU
template <int EPI>
__global__ __launch_bounds__(256) void agg256_kernel(
    const uint16_t* __restrict__ hin, uint16_t* __restrict__ hout,
    const int* __restrict__ off, const int* __restrict__ src,
    const float* __restrict__ val, const float* __restrict__ dinv,
    const float* __restrict__ bias, const float* __restrict__ g,
    const float* __restrict__ be, int n) {
  const int lane = threadIdx.x & 63;
  const int c = blockIdx.x * 4 + (threadIdx.x >> 6);
  if (c >= n) return;
  const int f = lane * 4;
  const int e0 = off[c], e1 = off[c + 1];
  const float di = dinv[c];
  const float s2 = di * di;
  float4 self = unpack_bf4(*(const uint2*)&hin[(size_t)c * 256 + f]);
  float4 acc = make_float4(self.x * s2, self.y * s2, self.z * s2, self.w * s2);

  for (int base = e0; base < e1; base += 64) {
    int idx = base + lane;
    int rs = 0; float rv = 0.0f;                 // zero-pad: row 0 x weight 0
    if (idx < e1) { rs = src[idx]; rv = val[idx]; }
    const int m = min(64, e1 - base);
    const int nG = (m + 3) >> 2;
    for (int gI = 0; gI < nG; ++gI) {
      int e_ = gI * 4;
      int s0 = __shfl(rs, e_);     float v0 = __shfl(rv, e_);
      int s1 = __shfl(rs, e_ + 1); float v1 = __shfl(rv, e_ + 1);
      int sB = __shfl(rs, e_ + 2); float v2 = __shfl(rv, e_ + 2);
      int s3 = __shfl(rs, e_ + 3); float v3 = __shfl(rv, e_ + 3);
      float4 h0 = unpack_bf4(*(const uint2*)&hin[(size_t)s0 * 256 + f]);
      float4 h1 = unpack_bf4(*(const uint2*)&hin[(size_t)s1 * 256 + f]);
      float4 h2 = unpack_bf4(*(const uint2*)&hin[(size_t)sB * 256 + f]);
      float4 h3 = unpack_bf4(*(const uint2*)&hin[(size_t)s3 * 256 + f]);
      acc.x += v0 * h0.x + v1 * h1.x + v2 * h2.x + v3 * h3.x;
      acc.y += v0 * h0.y + v1 * h1.y + v2 * h2.y + v3 * h3.y;
      acc.z += v0 * h0.z + v1 * h1.z + v2 * h2.z + v3 * h3.z;
      acc.w += v0 * h0.w + v1 * h1.w + v2 * h2.w + v3 * h3.w;
    }
  }

  if (EPI == 1) {
    const float bns = rsqrtf(1.0f + GCN_BN_EPS);
    float4 bi = *(const float4*)&bias[f];
    float4 gi = *(const float4*)&g[f];
    float4 bei = *(const float4*)&be[f];
    acc.x = fmaxf((acc.x + bi.x) * gi.x * bns + bei.x, 0.0f);
    acc.y = fmaxf((acc.y + bi.y) * gi.y * bns + bei.y, 0.0f);
    acc.z = fmaxf((acc.z + bi.z) * gi.z * bns + bei.z, 0.0f);
    acc.w = fmaxf((acc.w + bi.w) * gi.w * bns + bei.w, 0.0f);
  }
  *(uint2*)&hout[(size_t)c * 256 + f] = pack_bf4(acc);
}

// D=128 bf16: two nodes per wave (half-wave x 4 feats, 8B/lane).
// EPI 0: plain bf16 store. EPI 2: +bias, log_softmax -> fp32 out.
template <int EPI>
__global__ __launch_bounds__(256) void agg128_kernel(
    const uint16_t* __restrict__ hin, void* __restrict__ hout_,
    const int* __restrict__ off, const int* __restrict__ src,
    const float* __restrict__ val, const float* __restrict__ dinv,
    const float* __restrict__ bias, int n) {
  const int lane = threadIdx.x & 63;
  const int sub = lane & 31;
  const int hbase = lane & 32;
  const int c = blockIdx.x * 8 + (threadIdx.x >> 6) * 2 + (lane >> 5);
  const bool active = (c < n);
  const int f = sub * 4;

  int e0 = 0, e1 = 0;
  float4 acc = make_float4(0.f, 0.f, 0.f, 0.f);
  if (active) {
    e0 = off[c]; e1 = off[c + 1];
    float di = dinv[c];
    float s2 = di * di;
    float4 self = unpack_bf4(*(const uint2*)&hin[(size_t)c * 128 + f]);
    acc = make_float4(self.x * s2, self.y * s2, self.z * s2, self.w * s2);
  }
  int nch = (e1 - e0 + 31) >> 5;
  nch = max(nch, __shfl(nch, lane ^ 32));

  for (int ch = 0; ch < nch; ++ch) {
    int idx = e0 + ch * 32 + sub;
    int rs = 0; float rv = 0.0f;
    if (active && idx < e1) { rs = src[idx]; rv = val[idx]; }
    int m = e1 - (e0 + ch * 32);
    m = m < 0 ? 0 : (m > 32 ? 32 : m);
    int mMax = max(m, __shfl(m, lane ^ 32));
    const int nG = (mMax + 3) >> 2;
    for (int gI = 0; gI < nG; ++gI) {
      int e_ = hbase + gI * 4;
      int s0 = __shfl(rs, e_);     float v0 = __shfl(rv, e_);
      int s1 = __shfl(rs, e_ + 1); float v1 = __shfl(rv, e_ + 1);
      int sB = __shfl(rs, e_ + 2); float v2 = __shfl(rv, e_ + 2);
      int s3 = __shfl(rs, e_ + 3); float v3 = __shfl(rv, e_ + 3);
      float4 h0 = unpack_bf4(*(const uint2*)&hin[(size_t)s0 * 128 + f]);
      float4 h1 = unpack_bf4(*(const uint2*)&hin[(size_t)s1 * 128 + f]);
      float4 h2 = unpack_bf4(*(const uint2*)&hin[(size_t)sB * 128 + f]);
      float4 h3 = unpack_bf4(*(const uint2*)&hin[(size_t)s3 * 128 + f]);
      acc.x += v0 * h0.x + v1 * h1.x + v2 * h2.x + v3 * h3.x;
      acc.y += v0 * h0.y + v1 * h1.y + v2 * h2.y + v3 * h3.y;
      acc.z += v0 * h0.z + v1 * h1.z + v2 * h2.z + v3 * h3.z;
      acc.w += v0 * h0.w + v1 * h1.w + v2 * h2.w + v3 * h3.w;
    }
  }

  if (EPI == 0) {
    uint16_t* hout = (uint16_t*)hout_;
    if (active) *(uint2*)&hout[(size_t)c * 128 + f] = pack_bf4(acc);
  } else {
    float* hout = (float*)hout_;
    float4 bi = active ? *(const float4*)&bias[f] : make_float4(0.f, 0.f, 0.f, 0.f);
    float tx = acc.x + bi.x, ty = acc.y + bi.y, tz = acc.z + bi.z, tw = acc.w + bi.w;
    float mx = fmaxf(fmaxf(tx, ty), fmaxf(tz, tw));
#pragma unroll
    for (int s = 1; s < 32; s <<= 1) mx = fmaxf(mx, __shfl_xor(mx, s, 64));
    float ex = expf(tx - mx) + expf(ty - mx) + expf(tz - mx) + expf(tw - mx);
#pragma unroll
    for (int s = 1; s < 32; s <<= 1) ex += __shfl_xor(ex, s, 64);
    float lse = logf(ex) + mx;
    if (active) {
      float4 res = make_float4(tx - lse, ty - lse, tz - lse, tw - lse);
      *(float4*)&hout[(size_t)c * 128 + f] = res;
    }
  }
}

// ---------------------------------------------------------------- MFMA GEMM
// B-stationary: wave holds B-frags for its 64-col group across ALL of K in
// registers (loaded once), then streams 16-row A-tiles with depth-2 prefetch.
// 4 waves/block = 4 col groups of the SAME rows -> A hits L1, read once.
// mfma_f32_16x16x32_bf16 layouts: A lane(l): row=l&15, k=quad*8+j;
// B lane(l): col=l&15, k=quad*8+j (= WT[col][k..k+8]); C/D: col=l&15,
// row=quad*4+reg.
template <int K, int NC, int EPI>
__global__ __launch_bounds__(256) void mfma_gemm_kernel(
    const uint16_t* __restrict__ A, const uint16_t* __restrict__ WT,
    uint16_t* __restrict__ Cb, int M, int tpb,
    const float* __restrict__ bias, const float* __restrict__ g,
    const float* __restrict__ be) {
  constexpr int CW = NC / 4;   // columns per wave (64 for NC=256, 32 for NC=128)
  constexpr int NT = CW / 16;  // MFMA col-tiles per wave
  constexpr int KS = K / 32;   // MFMA k-steps
  const int lane = threadIdx.x & 63;
  const int wave = threadIdx.x >> 6;
  const int quad = lane >> 4;
  const int l16 = lane & 15;
  const int col0 = wave * CW;

  const int tiles = (M + 15) >> 4;
  int t0 = blockIdx.x * tpb;
  if (t0 >= tiles) return;
  int t1 = min(t0 + tpb, tiles);

  // B-frags: registers, loaded once
  v8bf b[KS][NT];
#pragma unroll
  for (int ks = 0; ks < KS; ++ks)
#pragma unroll
    for (int nt = 0; nt < NT; ++nt)
      b[ks][nt] = *(const v8bf*)(WT + (size_t)(col0 + nt * 16 + l16) * K +
                                 ks * 32 + quad * 8);

  // epilogue constants per column
  float sc[NT], o1[NT], o2[NT];
  if (EPI == 1) {
    const float bns = rsqrtf(1.0f + GCN_BN_EPS);
#pragma unroll
    for (int nt = 0; nt < NT; ++nt) {
      int col = col0 + nt * 16 + l16;
      sc[nt] = g[col] * bns; o1[nt] = bias[col]; o2[nt] = be[col];
    }
  }

  // depth-2 A prefetch across row-tiles
  v8bf a[KS], an[KS];
  {
    int arow = min(t0 * 16 + l16, M - 1);
    const uint16_t* Ap = A + (size_t)arow * K + quad * 8;
#pragma unroll
    for (int ks = 0; ks < KS; ++ks) a[ks] = *(const v8bf*)(Ap + ks * 32);
  }
  for (int t = t0; t < t1; ++t) {
    if (t + 1 < t1) {
      int arow = min((t + 1) * 16 + l16, M - 1);
      const uint16_t* Ap = A + (size_t)arow * K + quad * 8;
#pragma unroll
      for (int ks = 0; ks < KS; ++ks) an[ks] = *(const v8bf*)(Ap + ks * 32);
    }
    v4f acc[NT];
#pragma unroll
    for (int nt = 0; nt < NT; ++nt) acc[nt] = (v4f){0.f, 0.f, 0.f, 0.f};
#pragma unroll
    for (int ks = 0; ks < KS; ++ks)
#pragma unroll
      for (int nt = 0; nt < NT; ++nt)
        acc[nt] = __builtin_amdgcn_mfma_f32_16x16x32_bf16(a[ks], b[ks][nt],
                                                          acc[nt], 0, 0, 0);
    const int row0 = t * 16 + quad * 4;
#pragma unroll
    for (int nt = 0; nt < NT; ++nt) {
      const int col = col0 + nt * 16 + l16;
#pragma unroll
      for (int r = 0; r < 4; ++r) {
        int row = row0 + r;
        if (row < M) {
          float v = acc[nt][r];
          if (EPI == 1) v = fmaxf((v + o1[nt]) * sc[nt] + o2[nt], 0.0f);
          Cb[(size_t)row * NC + col] = f2bf(v);
        }
      }
    }
#pragma unroll
    for (int ks = 0; ks < KS; ++ks) a[ks] = an[ks];
  }
}

// ---------------------------------------------------------------- launch

static inline char* carve(char*& p, size_t bytes) {
  char* r = p;
  p += (bytes + 255) & ~(size_t)255;
  return r;
}

extern "C" void kernel_launch(void* const* d_in, const int* in_sizes, int n_in,
                              void* d_out, int out_size, void* d_ws, size_t ws_size,
                              hipStream_t stream) {
  const int N = in_sizes[0] / 128;
  const int E = in_sizes[2];

  const float* x  = (const float*)d_in[0];
  const int*   ei = (const int*)d_in[1];
  const float* ew = (const float*)d_in[2];
  const float* W0 = (const float*)d_in[3];
  const float* b0 = (const float*)d_in[4];
  const float* W1 = (const float*)d_in[5];
  const float* b1 = (const float*)d_in[6];
  const float* Wl = (const float*)d_in[7];
  const float* bl = (const float*)d_in[8];
  const float* g0 = (const float*)d_in[9];
  const float* be0 = (const float*)d_in[10];
  const float* g1 = (const float*)d_in[11];
  const float* be1 = (const float*)d_in[12];
  float* out = (float*)d_out;

  char* p = (char*)d_ws;
  float*    deg     = (float*)carve(p, (size_t)N * 4);
  float*    dinv    = (float*)carve(p, (size_t)N * 4);
  int*      cnt     = (int*)carve(p, (size_t)N * 4);
  int*      cursor  = (int*)carve(p, (size_t)N * 4);
  int*      off     = (int*)carve(p, (size_t)(N + 1) * 4);
  int*      flag    = (int*)carve(p, 256);
  int*      bsum    = (int*)carve(p, 1024 * 4);
  int*      row_    = (int*)carve(p, (size_t)E * 4);
  int*      col_    = (int*)carve(p, (size_t)E * 4);
  int*      csr_src = (int*)carve(p, (size_t)E * 4);
  float*    csr_val = (float*)carve(p, (size_t)E * 4);
  uint16_t* xb16    = (uint16_t*)carve(p, (size_t)N * 128 * 2);
  uint16_t* bufR    = (uint16_t*)carve(p, (size_t)N * 128 * 2);
  uint16_t* bufP    = (uint16_t*)carve(p, (size_t)N * 256 * 2);
  uint16_t* bufQ    = (uint16_t*)carve(p, (size_t)N * 256 * 2);
  uint16_t* W0t     = (uint16_t*)carve(p, (size_t)128 * 256 * 2);
  uint16_t* W1t     = (uint16_t*)carve(p, (size_t)256 * 256 * 2);
  uint16_t* Wlt     = (uint16_t*)carve(p, (size_t)256 * 128 * 2);

  const int TB = 256;
  const int gN = (N + TB - 1) / TB;
  const int gE = (E + TB - 1) / TB;
  const int gW4 = (N + 3) / 4;   // agg256: 4 nodes/block
  const int gW8 = (N + 7) / 8;   // agg128: 8 nodes/block
  const int tiles = (N + 15) / 16;
  const int TPB = 4;             // row-tiles per block
  const int gG = (tiles + TPB - 1) / TPB;  // ~782 blocks (~3/CU)

  // preprocessing + conversions
  init_detect_kernel<<<gN, TB, 0, stream>>>(deg, cnt, ei, flag, N);
  decode_deg_kernel<<<gE, TB, 0, stream>>>(ei, ew, flag, row_, col_, deg, cnt, E);
  scan1_kernel<<<gN, TB, 0, stream>>>(cnt, deg, dinv, bsum, N);
  scan2_kernel<<<1, 1024, 0, stream>>>(bsum, gN, off, N, E);
  scan3_kernel<<<gN, TB, 0, stream>>>(cnt, bsum, off, cursor, N);
  fill_kernel<<<gE, TB, 0, stream>>>(row_, col_, ew, dinv, cursor, csr_src, csr_val, E);
  conv_x_kernel<<<(N * 32 + TB - 1) / TB, TB, 0, stream>>>(x, xb16, N * 32);
  conv_wt_kernel<<<(128 * 256 + TB - 1) / TB, TB, 0, stream>>>(W0, W0t, 128, 256);
  conv_wt_kernel<<<(256 * 256 + TB - 1) / TB, TB, 0, stream>>>(W1, W1t, 256, 256);
  conv_wt_kernel<<<(256 * 128 + TB - 1) / TB, TB, 0, stream>>>(Wl, Wlt, 256, 128);

  // layer 0: agg(xb16,128) -> bufR; MFMA GEMM0 +BN0+ReLU -> bufP[N,256]
  agg128_kernel<0><<<gW8, 256, 0, stream>>>(xb16, bufR, off, csr_src, csr_val, dinv,
                                            nullptr, N);
  mfma_gemm_kernel<128, 256, 1><<<gG, 256, 0, stream>>>(bufR, W0t, bufP, N, TPB,
                                                        b0, g0, be0);
  // layer 1: GEMM1 -> bufQ; agg256 +b1+BN1+ReLU -> bufP
  mfma_gemm_kernel<256, 256, 0><<<gG, 256, 0, stream>>>(bufP, W1t, bufQ, N, TPB,
                                                        nullptr, nullptr, nullptr);
  agg256_kernel<1><<<gW4, 256, 0, stream>>>(bufQ, bufP, off, csr_src, csr_val, dinv,
                                            b1, g1, be1, N);
  // layer 2: GEMM2 -> bufR; agg128 +bl+log_softmax -> out (fp32)
  mfma_gemm_kernel<256, 128, 0><<<gG, 256, 0, stream>>>(bufP, Wlt, bufR, N, TPB,
                                                        nullptr, nullptr, nullptr);
  agg128_kernel<2><<<gW8, 256, 0, stream>>>(bufR, out, off, csr_src, csr_val, dinv,
                                            bl, N);
}